// Round 5
// baseline (246.517 us; speedup 1.0000x reference)
//
#include <hip/hip_runtime.h>
#include <hip/hip_bf16.h>
#include <math.h>

#define B_ 2
#define T_ 2048
#define E_ 1024
#define H_ 16
#define D_ 64
#define NT_ 32          // T/64 tiles
#define QSCALE 0.180336880f   // 0.125 * log2(e): folded into q so exp(S/8) = exp2(S')

typedef __attribute__((ext_vector_type(8))) short bf16x8;   // MFMA A/B frag (4 VGPRs)
typedef __attribute__((ext_vector_type(4))) float f32x4;    // MFMA C/D frag

#if __has_builtin(__builtin_amdgcn_exp2f)
#define EXP2(x) __builtin_amdgcn_exp2f(x)
#else
#define EXP2(x) exp2f(x)
#endif

__device__ __forceinline__ unsigned short f2bf(float x) {   // RNE fp32->bf16
  union { float f; unsigned u; } v; v.f = x;
  unsigned r = v.u + 0x7FFFu + ((v.u >> 16) & 1u);
  return (unsigned short)(r >> 16);
}
__device__ __forceinline__ unsigned pk2bf(float a, float b) {  // low=a, high=b (HW cvt_pk)
  __hip_bfloat162 h = __float22bfloat162_rn(make_float2(a, b));
  union { __hip_bfloat162 h; unsigned u; } c; c.h = h; return c.u;
}

// Async global->LDS: one wave-instr stages 8 rows x 64 bf16 (8 blocks of 16B),
// XOR-swizzled: LDS slot (row, bs) holds global block bs ^ (row&7).
__device__ __forceinline__ void dma8(const unsigned short* g, int gstride,
                                     unsigned short* l, int lane)
{
  const int r = lane >> 3, bg = (lane & 7) ^ (r & 7);
  __builtin_amdgcn_global_load_lds(
      (const __attribute__((address_space(1))) void*)(g + (size_t)r * gstride + bg * 8),
      (__attribute__((address_space(3))) void*)l, 16, 0, 0);
}
__device__ __forceinline__ bf16x8 frag(const unsigned short* tile, int row, int g) {
  return *(const bf16x8*)(tile + row * 64 + (((g ^ row) & 7) << 3));
}

// ---------------------------------------------------------------------------
// fused pack: blocks [0,2048) = input fp32->bf16; [2048,2816) = weight
// transpose (H,E,D) fp32 -> (H,D,E) bf16. Block 0 also zeroes the stats->out
// readiness mask (32 u32) for this iteration.
// ---------------------------------------------------------------------------
__global__ __launch_bounds__(256) void pack_kernel(
    const float* __restrict__ in, unsigned short* __restrict__ o16,
    const float* __restrict__ qw, const float* __restrict__ kw, const float* __restrict__ vw,
    unsigned short* __restrict__ qwt, unsigned short* __restrict__ kwt,
    unsigned short* __restrict__ vwt, unsigned int* __restrict__ mask)
{
  __shared__ float s[64][65];
  const int tid = threadIdx.x;
  if (blockIdx.x == 0 && tid < 32) mask[tid] = 0;   // flushed at kernel end
  if (blockIdx.x < 2048) {                       // input pack
    const size_t i = ((size_t)blockIdx.x * 256 + tid) * 8;
    float4 f0 = *(const float4*)(in + i);
    float4 f1 = *(const float4*)(in + i + 4);
    unsigned u[4] = { pk2bf(f0.x, f0.y), pk2bf(f0.z, f0.w),
                      pk2bf(f1.x, f1.y), pk2bf(f1.z, f1.w) };
    *(bf16x8*)(o16 + i) = *(const bf16x8*)u;
    return;
  }
  const int i = blockIdx.x - 2048;
  const int e0 = (i & 15) * 64, h = (i >> 4) & 15, z = i >> 8;
  const float* w = (z == 0) ? qw : (z == 1) ? kw : vw;
  unsigned short* o = (z == 0) ? qwt : (z == 1) ? kwt : vwt;
  {
    const int r = tid >> 2;
    #pragma unroll
    for (int p = 0; p < 4; ++p) {
      const int c = (tid & 3) * 4 + p * 16;
      float4 f = *(const float4*)(w + ((size_t)(h * E_ + e0 + r)) * D_ + c);
      s[r][c] = f.x; s[r][c+1] = f.y; s[r][c+2] = f.z; s[r][c+3] = f.w;
    }
  }
  __syncthreads();
  {
    const int d = tid >> 2, ec = (tid & 3) * 16;
    unsigned short tmp[16];
    #pragma unroll
    for (int j = 0; j < 16; ++j) tmp[j] = f2bf(s[ec + j][d]);
    unsigned short* dst = o + ((size_t)(h * D_ + d)) * E_ + e0 + ec;
    *(bf16x8*)(dst)     = *(const bf16x8*)&tmp[0];
    *(bf16x8*)(dst + 8) = *(const bf16x8*)&tmp[8];
  }
}

// ---------------------------------------------------------------------------
// QKV projection. grid (T/128, H, B) = 512. Wave retile: wave wv owns
// n-blocks {q:wv, k:wv, v:wv} (16-wide each, compile-time x) for ALL 128 t —
// 22 LDS frag reads/wave/iter, 48 MFMA. BK=64, dbuf dma8 staging.
// [round-1 form: best verified total 169.9 us]
// ---------------------------------------------------------------------------
__global__ __launch_bounds__(256) void proj_kernel(
    const unsigned short* __restrict__ in16,
    const unsigned short* __restrict__ qwt, const unsigned short* __restrict__ kwt,
    const unsigned short* __restrict__ vwt,
    const float* __restrict__ qb, const float* __restrict__ kb, const float* __restrict__ vb,
    unsigned short* __restrict__ qo, unsigned short* __restrict__ ko,
    unsigned short* __restrict__ vt)
{
  __shared__ __align__(16) unsigned short in_s[2][128 * 64];   // 32 KB
  __shared__ __align__(16) unsigned short w_s[2][3 * 64 * 64]; // 48 KB (flat rows: x*64+d)
  const int tid = threadIdx.x;
  const int lane = tid & 63, wv = tid >> 6;
  const int l15 = lane & 15, quad = lane >> 4;
  const int t0 = blockIdx.x * 128, h = blockIdx.y, b = blockIdx.z;
  const int bh = b * H_ + h;
  const unsigned short* wts[3] = { qwt, kwt, vwt };

  f32x4 acc[3][8];
  #pragma unroll
  for (int x = 0; x < 3; ++x)
    #pragma unroll
    for (int tb = 0; tb < 8; ++tb) acc[x][tb] = (f32x4){0.f, 0.f, 0.f, 0.f};

#define PROJ_STAGE(e0_, bi_)                                                      \
  {                                                                               \
    const unsigned short* gin = in16 + ((size_t)(b * T_ + t0)) * E_ + (e0_);      \
    _Pragma("unroll")                                                             \
    for (int p = 0; p < 4; ++p) {                                                 \
      const int br = wv * 32 + p * 8;                                             \
      dma8(gin + (size_t)br * E_, E_, &in_s[bi_][br * 64], lane);                 \
    }                                                                             \
    _Pragma("unroll")                                                             \
    for (int j = 0; j < 6; ++j) {                                                 \
      const int idx = wv * 6 + j;                                                 \
      const int x = idx >> 3, br = (idx & 7) * 8;                                 \
      dma8(wts[x] + ((size_t)(h * D_ + br)) * E_ + (e0_), E_,                     \
           &w_s[bi_][x * 4096 + br * 64], lane);                                  \
    }                                                                             \
  }

  PROJ_STAGE(0, 0);
  __syncthreads();
  for (int e = 0; e < 16; ++e) {
    const int bi = e & 1;
    if (e < 15) PROJ_STAGE((e + 1) * 64, bi ^ 1);
    const unsigned short* is = in_s[bi];
    const unsigned short* ws = w_s[bi];
    #pragma unroll
    for (int kk = 0; kk < 2; ++kk) {
      const int g0 = kk * 4 + quad;
      bf16x8 bfr[3];
      #pragma unroll
      for (int x = 0; x < 3; ++x)
        bfr[x] = frag(ws, x * 64 + wv * 16 + l15, g0);
      bf16x8 afr[8];
      #pragma unroll
      for (int tb = 0; tb < 8; ++tb)
        afr[tb] = frag(is, tb * 16 + l15, g0);
      #pragma unroll
      for (int tb = 0; tb < 8; ++tb) {
        // q,k: A=w (m=d), B=in (n=t) -> C col=t; v: A=in (m=t), B=w -> C col=d
        acc[0][tb] = __builtin_amdgcn_mfma_f32_16x16x32_bf16(bfr[0], afr[tb], acc[0][tb], 0, 0, 0);
        acc[1][tb] = __builtin_amdgcn_mfma_f32_16x16x32_bf16(bfr[1], afr[tb], acc[1][tb], 0, 0, 0);
        acc[2][tb] = __builtin_amdgcn_mfma_f32_16x16x32_bf16(afr[tb], bfr[2], acc[2][tb], 0, 0, 0);
      }
    }
    __syncthreads();
  }
#undef PROJ_STAGE

  const size_t obase = (size_t)bh * T_;
  // q (scaled) and k: lane t = tb*16+l15, 4 consecutive d -> ushort4 stores
  #pragma unroll
  for (int x = 0; x < 2; ++x) {
    const float scl = (x == 0) ? QSCALE : 1.0f;
    const float* bias = (x == 0) ? qb : kb;
    unsigned short* outp = (x == 0) ? qo : ko;
    float bias4[4];
    *(float4*)bias4 = *(const float4*)&bias[h * D_ + wv * 16 + quad * 4];
    #pragma unroll
    for (int tb = 0; tb < 8; ++tb) {
      const int t = t0 + tb * 16 + l15;
      unsigned short pk[4];
      #pragma unroll
      for (int r = 0; r < 4; ++r) pk[r] = f2bf((acc[x][tb][r] + bias4[r]) * scl);
      *(ushort4*)(outp + (obase + t) * D_ + wv * 16 + quad * 4) = *(const ushort4*)pk;
    }
  }
  // v: transposed [d][t] — lane d = wv*16+l15, 4 consecutive t -> ushort4
  {
    const int d = wv * 16 + l15;
    const float bvv = vb[h * D_ + d];
    #pragma unroll
    for (int tb = 0; tb < 8; ++tb) {
      const int t = t0 + tb * 16 + quad * 4;
      unsigned short pk[4];
      #pragma unroll
      for (int r = 0; r < 4; ++r) pk[r] = f2bf(acc[2][tb][r] + bvv);
      *(ushort4*)(vt + ((size_t)(bh * D_ + d)) * T_ + t) = *(const ushort4*)pk;
    }
  }
}

// ---------------------------------------------------------------------------
// FUSED stats+out. Flat grid 2048. Blocks [0,1024): stats role (sa = idx>>5,
// heavy sa=0 first); blocks [1024,2048): out role (jt = 31 - (j>>5), heavy
// first). stats publishes each 64-col lg slab via agent-scope atomic stores
// then atomicOr-release of bit sa into mask[bh]; out spins (tid 0, s_sleep)
// on the acquire-loaded mask for bits 0..jt, then runs the round-1 out body.
// In-order dispatch => all stats blocks allocated before any out block =>
// resident blocks always progress (no deadlock). Agent-scope atomics bypass
// the non-coherent per-XCD L2 (incl. stale fill poison). LDS: union of the
// stats (17.4 KB) and out (42.5 KB) layouts in one 43520-B pool -> 3 blk/CU.
// ---------------------------------------------------------------------------
__global__ __launch_bounds__(256) void attn_kernel(
    const unsigned short* __restrict__ q, const unsigned short* __restrict__ k,
    const unsigned short* __restrict__ vt, float* __restrict__ lg,
    unsigned int* __restrict__ mask, float* __restrict__ out)
{
  __shared__ __align__(16) unsigned char smem[43520];
  const int tid = threadIdx.x;
  const int lane = tid & 63, wv = tid >> 6;
  const int l15 = lane & 15, quad = lane >> 4;
  const int bidx = blockIdx.x;

  if (bidx < 1024) {
    // ------------------------------ stats role ------------------------------
    unsigned short (*q_s)[64 * 64] = (unsigned short (*)[64 * 64])smem;  // 16 KB
    float (*red)[64] = (float (*)[64])(smem + 16384);                    // 1 KB
    const int h = bidx & 15, b = (bidx >> 4) & 1, sa = bidx >> 5;
    const int bh = b * H_ + h;
    const int s0 = sa * 64;
    const unsigned short* qbase = q + (size_t)bh * T_ * 64;

    bf16x8 kf[4][2];                             // reg-resident K B-frags
    #pragma unroll
    for (int nb = 0; nb < 4; ++nb)
      #pragma unroll
      for (int kk = 0; kk < 2; ++kk)
        kf[nb][kk] = *(const bf16x8*)(k + ((size_t)(bh * T_ + s0 + nb * 16 + l15)) * 64
                                        + kk * 32 + quad * 8);

    #pragma unroll
    for (int pp = 0; pp < 2; ++pp) {
      const int br = wv * 16 + pp * 8;
      dma8(qbase + (size_t)(sa * 64 + br) * 64, 64, &q_s[0][br * 64], lane);
    }
    __syncthreads();

    float lsum[4] = {0.f, 0.f, 0.f, 0.f};

    for (int tt = sa, i = 0; tt < NT_; ++tt, ++i) {
      const int bi = i & 1;
      if (tt + 1 < NT_) {
        #pragma unroll
        for (int pp = 0; pp < 2; ++pp) {
          const int br = wv * 16 + pp * 8;
          dma8(qbase + (size_t)((tt + 1) * 64 + br) * 64, 64, &q_s[bi ^ 1][br * 64], lane);
        }
      }
      bf16x8 a0 = frag(q_s[bi], wv * 16 + l15, quad);
      bf16x8 a1 = frag(q_s[bi], wv * 16 + l15, 4 + quad);
      f32x4 sacc[4];
      #pragma unroll
      for (int nb = 0; nb < 4; ++nb) sacc[nb] = (f32x4){0.f, 0.f, 0.f, 0.f};
      #pragma unroll
      for (int nb = 0; nb < 4; ++nb) {
        sacc[nb] = __builtin_amdgcn_mfma_f32_16x16x32_bf16(a0, kf[nb][0], sacc[nb], 0, 0, 0);
        sacc[nb] = __builtin_amdgcn_mfma_f32_16x16x32_bf16(a1, kf[nb][1], sacc[nb], 0, 0, 0);
      }
      if (tt == sa) {                            // diagonal tile: causal mask
        const int tbase = tt * 64 + wv * 16 + quad * 4;
        #pragma unroll
        for (int nb = 0; nb < 4; ++nb) {
          const int s = s0 + nb * 16 + l15;
          #pragma unroll
          for (int r = 0; r < 4; ++r)
            lsum[nb] += (tbase + r >= s) ? EXP2(sacc[nb][r]) : 0.f;
        }
      } else {
        #pragma unroll
        for (int nb = 0; nb < 4; ++nb)
          #pragma unroll
          for (int r = 0; r < 4; ++r) lsum[nb] += EXP2(sacc[nb][r]);
      }
      __syncthreads();
    }
    #pragma unroll
    for (int nb = 0; nb < 4; ++nb) {
      lsum[nb] += __shfl_xor(lsum[nb], 16);
      lsum[nb] += __shfl_xor(lsum[nb], 32);
    }
    if (lane < 16) {
      #pragma unroll
      for (int nb = 0; nb < 4; ++nb) red[wv][nb * 16 + lane] = lsum[nb];
    }
    __syncthreads();
    if (tid < 64) {
      const float L = red[0][tid] + red[1][tid] + red[2][tid] + red[3][tid];
      __hip_atomic_store(&lg[(size_t)bh * T_ + s0 + tid], -__log2f(L),
                         __ATOMIC_RELAXED, __HIP_MEMORY_SCOPE_AGENT);
    }
    __syncthreads();                             // all 64 stores retired
    if (tid == 0)
      __hip_atomic_fetch_or(&mask[bh], 1u << sa, __ATOMIC_RELEASE,
                            __HIP_MEMORY_SCOPE_AGENT);
    return;
  }

  // -------------------------------- out role --------------------------------
  unsigned short (*k_s)[4096]  = (unsigned short (*)[4096])smem;              // 16 KB
  unsigned short (*vt_s)[4096] = (unsigned short (*)[4096])(smem + 16384);    // 16 KB
  unsigned short (*u_s)[32][40] = (unsigned short (*)[32][40])(smem + 32768); // 10 KB
  float (*lg_sh)[64] = (float (*)[64])(smem + 43008);                         // 512 B

  const int j = bidx - 1024;
  const int h = j & 15, b = (j >> 4) & 1, jt = 31 - (j >> 5);
  const int th = wv >> 1, sh = wv & 1;           // wave's t-half / s-half
  const int bh = b * H_ + h;
  const int t0 = jt * 64;
  const unsigned short* kbase = k + (size_t)bh * T_ * 64;
  const unsigned short* vbase = vt + (size_t)bh * D_ * T_;
  const float* lgbase = lg + (size_t)bh * T_;

  // wait for all needed lg slabs (sa = 0..jt) of this (b,h)
  if (tid == 0) {
    const unsigned need = (jt >= 31) ? 0xFFFFFFFFu : ((2u << jt) - 1u);
    while ((__hip_atomic_load(&mask[bh], __ATOMIC_ACQUIRE,
                              __HIP_MEMORY_SCOPE_AGENT) & need) != need)
      __builtin_amdgcn_s_sleep(8);
  }
  __syncthreads();

  // one-time Q B-frags: this wave's 32 t-cols (2 n-tiles x 2 k-steps)
  bf16x8 qf[2][2];
  #pragma unroll
  for (int nt = 0; nt < 2; ++nt) {
    const unsigned short* qrow = q + (size_t)(bh * T_ + t0 + th * 32 + nt * 16 + l15) * 64;
    qf[nt][0] = *(const bf16x8*)(qrow + quad * 8);
    qf[nt][1] = *(const bf16x8*)(qrow + 32 + quad * 8);
  }

  // stage unit 0 into slot 0
  #pragma unroll
  for (int pp = 0; pp < 2; ++pp) {
    const int br = wv * 16 + pp * 8;
    dma8(kbase + (size_t)br * 64, 64, &k_s[0][br * 64], lane);
    dma8(vbase + (size_t)br * T_, T_, &vt_s[0][br * 64], lane);
  }
  if (tid < 64)
    lg_sh[0][tid] = __hip_atomic_load(&lgbase[tid], __ATOMIC_RELAXED,
                                      __HIP_MEMORY_SCOPE_AGENT);
  __syncthreads();

  f32x4 oacc[4][2];                              // [d-tile][t-tile of own half]
  #pragma unroll
  for (int mb = 0; mb < 4; ++mb)
    #pragma unroll
    for (int nt = 0; nt < 2; ++nt) oacc[mb][nt] = (f32x4){0.f, 0.f, 0.f, 0.f};

  for (int st = 0; st <= jt; ++st) {
    const int bi = st & 1;
    if (st < jt) {                               // prefetch next unit
      const int s1 = (st + 1) * 64;
      #pragma unroll
      for (int pp = 0; pp < 2; ++pp) {
        const int br = wv * 16 + pp * 8;
        dma8(kbase + (size_t)(s1 + br) * 64, 64, &k_s[bi ^ 1][br * 64], lane);
        dma8(vbase + (size_t)br * T_ + s1, T_, &vt_s[bi ^ 1][br * 64], lane);
      }
      if (tid < 64)
        lg_sh[bi ^ 1][tid] = __hip_atomic_load(&lgbase[s1 + tid], __ATOMIC_RELAXED,
                                               __HIP_MEMORY_SCOPE_AGENT);
    }
    const unsigned short* ks = k_s[bi];
    const unsigned short* vs = vt_s[bi];
    const float* lgb = lg_sh[bi];

    const bool dead = (st == jt) && (th == 0) && (sh == 1);  // fully-masked quadrant
    if (!dead) {
      // S^T quadrant: A = K rows (own s-half), B = Q (reg); C init = lg[s]
      f32x4 sacc[2][2];
      #pragma unroll
      for (int mb = 0; mb < 2; ++mb) {
        float lg4[4];
        *(float4*)lg4 = *(const float4*)&lgb[sh * 32 + mb * 16 + quad * 4];
        #pragma unroll
        for (int nt = 0; nt < 2; ++nt)
          sacc[mb][nt] = (f32x4){lg4[0], lg4[1], lg4[2], lg4[3]};
      }
      #pragma unroll
      for (int mb = 0; mb < 2; ++mb) {
        bf16x8 ka0 = frag(ks, sh * 32 + mb * 16 + l15, quad);
        bf16x8 ka1 = frag(ks, sh * 32 + mb * 16 + l15, 4 + quad);
        #pragma unroll
        for (int nt = 0; nt < 2; ++nt) {
          sacc[mb][nt] = __builtin_amdgcn_mfma_f32_16x16x32_bf16(ka0, qf[nt][0], sacc[mb][nt], 0, 0, 0);
          sacc[mb][nt] = __builtin_amdgcn_mfma_f32_16x16x32_bf16(ka1, qf[nt][1], sacc[mb][nt], 0, 0, 0);
        }
      }
      // U = exp2(S' + lg[s]); diagonal quadrants (th==sh) masked elementwise
      const bool diagmask = (st == jt) && (th == sh);
      #pragma unroll
      for (int mb = 0; mb < 2; ++mb)
        #pragma unroll
        for (int nt = 0; nt < 2; ++nt) {
          float uu[4] = { EXP2(sacc[mb][nt][0]), EXP2(sacc[mb][nt][1]),
                          EXP2(sacc[mb][nt][2]), EXP2(sacc[mb][nt][3]) };
          if (diagmask) {
            const int tl = nt * 16 + l15, sl = mb * 16 + quad * 4;
            #pragma unroll
            for (int r = 0; r < 4; ++r) if (tl < sl + r) uu[r] = 0.f;
          }
          *(uint2*)(&u_s[wv][nt * 16 + l15][mb * 16 + quad * 4]) =
              make_uint2(pk2bf(uu[0], uu[1]), pk2bf(uu[2], uu[3]));
        }
      // O^T partial += Vt[:, own s-half] . U^T — same-wave LDS dep, K-dim=32
      #pragma unroll
      for (int nt = 0; nt < 2; ++nt) {
        bf16x8 ua = *(const bf16x8*)(&u_s[wv][nt * 16 + l15][quad * 8]);
        #pragma unroll
        for (int mb = 0; mb < 4; ++mb)
          oacc[mb][nt] = __builtin_amdgcn_mfma_f32_16x16x32_bf16(
              frag(vs, mb * 16 + l15, sh * 4 + quad), ua, oacc[mb][nt], 0, 0, 0);
      }
    }
    __syncthreads();   // waves done with slot bi; prefetch into bi^1 drained
  }

  // cross-wave reduce over s-halves: sh=1 writes partials to retired k_s (fp32)
  float* scr = (float*)k_s;                      // 16 KB = 2 th x 8 acc x 64 lanes x 16B
  if (sh == 1) {
    #pragma unroll
    for (int mb = 0; mb < 4; ++mb)
      #pragma unroll
      for (int nt = 0; nt < 2; ++nt) {
        float o4[4] = { oacc[mb][nt][0], oacc[mb][nt][1], oacc[mb][nt][2], oacc[mb][nt][3] };
        *(float4*)&scr[((th * 8 + mb * 2 + nt) * 64 + lane) * 4] = *(const float4*)o4;
      }
  }
  __syncthreads();
  if (sh == 0) {
    #pragma unroll
    for (int nt = 0; nt < 2; ++nt) {
      float* orow = out + ((size_t)(b * T_ + t0 + th * 32 + nt * 16 + l15)) * (H_ * D_) + h * D_;
      #pragma unroll
      for (int mb = 0; mb < 4; ++mb) {
        float4 p = *(const float4*)&scr[((th * 8 + mb * 2 + nt) * 64 + lane) * 4];
        float o4[4] = { oacc[mb][nt][0] + p.x, oacc[mb][nt][1] + p.y,
                        oacc[mb][nt][2] + p.z, oacc[mb][nt][3] + p.w };
        *(float4*)(orow + mb * 16 + quad * 4) = *(const float4*)o4;
      }
    }
  }
}

extern "C" void kernel_launch(void* const* d_in, const int* in_sizes, int n_in,
                              void* d_out, int out_size, void* d_ws, size_t ws_size,
                              hipStream_t stream) {
  const float* in = (const float*)d_in[0];
  const float* kw = (const float*)d_in[1];
  const float* kb = (const float*)d_in[2];
  const float* qw = (const float*)d_in[3];
  const float* qb = (const float*)d_in[4];
  const float* vw = (const float*)d_in[5];
  const float* vb = (const float*)d_in[6];
  float* out = (float*)d_out;

  // ws (bf16): in16 | qwt|kwt|vwt (H,D,E) | q16|k16 (B,H,T,D) | vt (B,H,D,T) |
  //            lg fp32 (B*H*T) | mask u32[32]
  unsigned short* p = (unsigned short*)d_ws;
  const size_t inz = (size_t)B_ * T_ * E_;
  const size_t wz  = (size_t)H_ * D_ * E_;
  const size_t qz  = (size_t)B_ * H_ * T_ * D_;
  unsigned short* in16 = p;            p += inz;
  unsigned short* qwt  = p;            p += wz;
  unsigned short* kwt  = p;            p += wz;
  unsigned short* vwt  = p;            p += wz;
  unsigned short* q16  = p;            p += qz;
  unsigned short* k16  = p;            p += qz;
  unsigned short* vtb  = p;            p += qz;
  float* lgbuf = (float*)p;
  unsigned int* maskbuf = (unsigned int*)(lgbuf + (size_t)B_ * H_ * T_);

  dim3 blk(256);
  pack_kernel <<<dim3(2048 + 768), blk, 0, stream>>>(in, in16, qw, kw, vw,
                                                     qwt, kwt, vwt, maskbuf);
  proj_kernel <<<dim3(T_ / 128, H_, B_), blk, 0, stream>>>(in16, qwt, kwt, vwt,
                                                           qb, kb, vb, q16, k16, vtb);
  attn_kernel <<<dim3(2048), blk, 0, stream>>>(q16, k16, vtb, lgbuf, maskbuf, out);
}

// Round 6
// 172.094 us; speedup vs baseline: 1.4324x; 1.4324x over previous
//
#include <hip/hip_runtime.h>
#include <hip/hip_bf16.h>
#include <math.h>

#define B_ 2
#define T_ 2048
#define E_ 1024
#define H_ 16
#define D_ 64
#define NT_ 32          // T/64 tiles
#define QSCALE 0.180336880f   // 0.125 * log2(e): folded into q so exp(S/8) = exp2(S')

typedef __attribute__((ext_vector_type(8))) short bf16x8;   // MFMA A/B frag (4 VGPRs)
typedef __attribute__((ext_vector_type(4))) float f32x4;    // MFMA C/D frag

#if __has_builtin(__builtin_amdgcn_exp2f)
#define EXP2(x) __builtin_amdgcn_exp2f(x)
#else
#define EXP2(x) exp2f(x)
#endif

__device__ __forceinline__ unsigned short f2bf(float x) {   // RNE fp32->bf16
  union { float f; unsigned u; } v; v.f = x;
  unsigned r = v.u + 0x7FFFu + ((v.u >> 16) & 1u);
  return (unsigned short)(r >> 16);
}
__device__ __forceinline__ unsigned pk2bf(float a, float b) {  // low=a, high=b (HW cvt_pk)
  __hip_bfloat162 h = __float22bfloat162_rn(make_float2(a, b));
  union { __hip_bfloat162 h; unsigned u; } c; c.h = h; return c.u;
}

// Async global->LDS: one wave-instr stages 8 rows x 64 bf16 (8 blocks of 16B),
// XOR-swizzled: LDS slot (row, bs) holds global block bs ^ (row&7).
__device__ __forceinline__ void dma8(const unsigned short* g, int gstride,
                                     unsigned short* l, int lane)
{
  const int r = lane >> 3, bg = (lane & 7) ^ (r & 7);
  __builtin_amdgcn_global_load_lds(
      (const __attribute__((address_space(1))) void*)(g + (size_t)r * gstride + bg * 8),
      (__attribute__((address_space(3))) void*)l, 16, 0, 0);
}
__device__ __forceinline__ bf16x8 frag(const unsigned short* tile, int row, int g) {
  return *(const bf16x8*)(tile + row * 64 + (((g ^ row) & 7) << 3));
}

// ---------------------------------------------------------------------------
// fused pack: blocks [0,2048) = input fp32->bf16; [2048,2816) = weight
// transpose (H,E,D) fp32 -> (H,D,E) bf16.
// ---------------------------------------------------------------------------
__global__ __launch_bounds__(256) void pack_kernel(
    const float* __restrict__ in, unsigned short* __restrict__ o16,
    const float* __restrict__ qw, const float* __restrict__ kw, const float* __restrict__ vw,
    unsigned short* __restrict__ qwt, unsigned short* __restrict__ kwt,
    unsigned short* __restrict__ vwt)
{
  __shared__ float s[64][65];
  const int tid = threadIdx.x;
  if (blockIdx.x < 2048) {                       // input pack
    const size_t i = ((size_t)blockIdx.x * 256 + tid) * 8;
    float4 f0 = *(const float4*)(in + i);
    float4 f1 = *(const float4*)(in + i + 4);
    unsigned u[4] = { pk2bf(f0.x, f0.y), pk2bf(f0.z, f0.w),
                      pk2bf(f1.x, f1.y), pk2bf(f1.z, f1.w) };
    *(bf16x8*)(o16 + i) = *(const bf16x8*)u;
    return;
  }
  const int i = blockIdx.x - 2048;
  const int e0 = (i & 15) * 64, h = (i >> 4) & 15, z = i >> 8;
  const float* w = (z == 0) ? qw : (z == 1) ? kw : vw;
  unsigned short* o = (z == 0) ? qwt : (z == 1) ? kwt : vwt;
  {
    const int r = tid >> 2;
    #pragma unroll
    for (int p = 0; p < 4; ++p) {
      const int c = (tid & 3) * 4 + p * 16;
      float4 f = *(const float4*)(w + ((size_t)(h * E_ + e0 + r)) * D_ + c);
      s[r][c] = f.x; s[r][c+1] = f.y; s[r][c+2] = f.z; s[r][c+3] = f.w;
    }
  }
  __syncthreads();
  {
    const int d = tid >> 2, ec = (tid & 3) * 16;
    unsigned short tmp[16];
    #pragma unroll
    for (int j = 0; j < 16; ++j) tmp[j] = f2bf(s[ec + j][d]);
    unsigned short* dst = o + ((size_t)(h * D_ + d)) * E_ + e0 + ec;
    *(bf16x8*)(dst)     = *(const bf16x8*)&tmp[0];
    *(bf16x8*)(dst + 8) = *(const bf16x8*)&tmp[8];
  }
}

// ---------------------------------------------------------------------------
// QKV projection. grid (T/128, H, B) = 512. Wave retile: wave wv owns
// n-blocks {q:wv, k:wv, v:wv} (16-wide each, compile-time x) for ALL 128 t —
// 22 LDS frag reads/wave/iter, 48 MFMA. BK=64, dbuf dma8 staging.
// [round-1 form: best verified total 169.9 us — do not perturb]
// ---------------------------------------------------------------------------
__global__ __launch_bounds__(256) void proj_kernel(
    const unsigned short* __restrict__ in16,
    const unsigned short* __restrict__ qwt, const unsigned short* __restrict__ kwt,
    const unsigned short* __restrict__ vwt,
    const float* __restrict__ qb, const float* __restrict__ kb, const float* __restrict__ vb,
    unsigned short* __restrict__ qo, unsigned short* __restrict__ ko,
    unsigned short* __restrict__ vt)
{
  __shared__ __align__(16) unsigned short in_s[2][128 * 64];   // 32 KB
  __shared__ __align__(16) unsigned short w_s[2][3 * 64 * 64]; // 48 KB (flat rows: x*64+d)
  const int tid = threadIdx.x;
  const int lane = tid & 63, wv = tid >> 6;
  const int l15 = lane & 15, quad = lane >> 4;
  const int t0 = blockIdx.x * 128, h = blockIdx.y, b = blockIdx.z;
  const int bh = b * H_ + h;
  const unsigned short* wts[3] = { qwt, kwt, vwt };

  f32x4 acc[3][8];
  #pragma unroll
  for (int x = 0; x < 3; ++x)
    #pragma unroll
    for (int tb = 0; tb < 8; ++tb) acc[x][tb] = (f32x4){0.f, 0.f, 0.f, 0.f};

#define PROJ_STAGE(e0_, bi_)                                                      \
  {                                                                               \
    const unsigned short* gin = in16 + ((size_t)(b * T_ + t0)) * E_ + (e0_);      \
    _Pragma("unroll")                                                             \
    for (int p = 0; p < 4; ++p) {                                                 \
      const int br = wv * 32 + p * 8;                                             \
      dma8(gin + (size_t)br * E_, E_, &in_s[bi_][br * 64], lane);                 \
    }                                                                             \
    _Pragma("unroll")                                                             \
    for (int j = 0; j < 6; ++j) {                                                 \
      const int idx = wv * 6 + j;                                                 \
      const int x = idx >> 3, br = (idx & 7) * 8;                                 \
      dma8(wts[x] + ((size_t)(h * D_ + br)) * E_ + (e0_), E_,                     \
           &w_s[bi_][x * 4096 + br * 64], lane);                                  \
    }                                                                             \
  }

  PROJ_STAGE(0, 0);
  __syncthreads();
  for (int e = 0; e < 16; ++e) {
    const int bi = e & 1;
    if (e < 15) PROJ_STAGE((e + 1) * 64, bi ^ 1);
    const unsigned short* is = in_s[bi];
    const unsigned short* ws = w_s[bi];
    #pragma unroll
    for (int kk = 0; kk < 2; ++kk) {
      const int g0 = kk * 4 + quad;
      bf16x8 bfr[3];
      #pragma unroll
      for (int x = 0; x < 3; ++x)
        bfr[x] = frag(ws, x * 64 + wv * 16 + l15, g0);
      bf16x8 afr[8];
      #pragma unroll
      for (int tb = 0; tb < 8; ++tb)
        afr[tb] = frag(is, tb * 16 + l15, g0);
      #pragma unroll
      for (int tb = 0; tb < 8; ++tb) {
        // q,k: A=w (m=d), B=in (n=t) -> C col=t; v: A=in (m=t), B=w -> C col=d
        acc[0][tb] = __builtin_amdgcn_mfma_f32_16x16x32_bf16(bfr[0], afr[tb], acc[0][tb], 0, 0, 0);
        acc[1][tb] = __builtin_amdgcn_mfma_f32_16x16x32_bf16(bfr[1], afr[tb], acc[1][tb], 0, 0, 0);
        acc[2][tb] = __builtin_amdgcn_mfma_f32_16x16x32_bf16(afr[tb], bfr[2], acc[2][tb], 0, 0, 0);
      }
    }
    __syncthreads();
  }
#undef PROJ_STAGE

  const size_t obase = (size_t)bh * T_;
  // q (scaled) and k: lane t = tb*16+l15, 4 consecutive d -> ushort4 stores
  #pragma unroll
  for (int x = 0; x < 2; ++x) {
    const float scl = (x == 0) ? QSCALE : 1.0f;
    const float* bias = (x == 0) ? qb : kb;
    unsigned short* outp = (x == 0) ? qo : ko;
    float bias4[4];
    *(float4*)bias4 = *(const float4*)&bias[h * D_ + wv * 16 + quad * 4];
    #pragma unroll
    for (int tb = 0; tb < 8; ++tb) {
      const int t = t0 + tb * 16 + l15;
      unsigned short pk[4];
      #pragma unroll
      for (int r = 0; r < 4; ++r) pk[r] = f2bf((acc[x][tb][r] + bias4[r]) * scl);
      *(ushort4*)(outp + (obase + t) * D_ + wv * 16 + quad * 4) = *(const ushort4*)pk;
    }
  }
  // v: transposed [d][t] — lane d = wv*16+l15, 4 consecutive t -> ushort4
  {
    const int d = wv * 16 + l15;
    const float bvv = vb[h * D_ + d];
    #pragma unroll
    for (int tb = 0; tb < 8; ++tb) {
      const int t = t0 + tb * 16 + quad * 4;
      unsigned short pk[4];
      #pragma unroll
      for (int r = 0; r < 4; ++r) pk[r] = f2bf(acc[2][tb][r] + bvv);
      *(ushort4*)(vt + ((size_t)(bh * D_ + d)) * T_ + t) = *(const ushort4*)pk;
    }
  }
}

// ---------------------------------------------------------------------------
// Column softmax: lg[s] = -log2( sum_t exp2(S'[t,s]) ). grid (H, B, NT) =
// 1024 blocks, 4/CU; sa=0 (heaviest) first. K B-frags reg-resident
// (one-time), Q dbuf via dma8. 16.5 KB LDS. [round-1 form + setprio(T5):
// independent blocks per CU at different phases -> scheduler can favor
// MFMA-entering waves]
// ---------------------------------------------------------------------------
__global__ __launch_bounds__(256) void stats_kernel(
    const unsigned short* __restrict__ q, const unsigned short* __restrict__ k,
    float* __restrict__ lg)
{
  __shared__ __align__(16) unsigned short q_s[2][64 * 64];   // 16 KB
  __shared__ float red[4][64];
  const int tid = threadIdx.x;
  const int lane = tid & 63, wv = tid >> 6;
  const int l15 = lane & 15, quad = lane >> 4;
  const int h = blockIdx.x, b = blockIdx.y, sa = blockIdx.z;
  const int bh = b * H_ + h;
  const int s0 = sa * 64;
  const unsigned short* qbase = q + (size_t)bh * T_ * 64;

  bf16x8 kf[4][2];                               // reg-resident K B-frags (one-time)
  #pragma unroll
  for (int nb = 0; nb < 4; ++nb)
    #pragma unroll
    for (int kk = 0; kk < 2; ++kk)
      kf[nb][kk] = *(const bf16x8*)(k + ((size_t)(bh * T_ + s0 + nb * 16 + l15)) * 64
                                      + kk * 32 + quad * 8);

  #pragma unroll
  for (int pp = 0; pp < 2; ++pp) {
    const int br = wv * 16 + pp * 8;
    dma8(qbase + (size_t)(sa * 64 + br) * 64, 64, &q_s[0][br * 64], lane);
  }
  __syncthreads();

  float lsum[4] = {0.f, 0.f, 0.f, 0.f};

  for (int tt = sa, i = 0; tt < NT_; ++tt, ++i) {
    const int bi = i & 1;
    if (tt + 1 < NT_) {
      #pragma unroll
      for (int pp = 0; pp < 2; ++pp) {
        const int br = wv * 16 + pp * 8;
        dma8(qbase + (size_t)((tt + 1) * 64 + br) * 64, 64, &q_s[bi ^ 1][br * 64], lane);
      }
    }
    bf16x8 a0 = frag(q_s[bi], wv * 16 + l15, quad);
    bf16x8 a1 = frag(q_s[bi], wv * 16 + l15, 4 + quad);
    f32x4 sacc[4];
    #pragma unroll
    for (int nb = 0; nb < 4; ++nb) sacc[nb] = (f32x4){0.f, 0.f, 0.f, 0.f};
    __builtin_amdgcn_s_setprio(1);
    #pragma unroll
    for (int nb = 0; nb < 4; ++nb) {
      sacc[nb] = __builtin_amdgcn_mfma_f32_16x16x32_bf16(a0, kf[nb][0], sacc[nb], 0, 0, 0);
      sacc[nb] = __builtin_amdgcn_mfma_f32_16x16x32_bf16(a1, kf[nb][1], sacc[nb], 0, 0, 0);
    }
    __builtin_amdgcn_s_setprio(0);
    if (tt == sa) {                              // diagonal tile: causal mask
      const int tbase = tt * 64 + wv * 16 + quad * 4;
      #pragma unroll
      for (int nb = 0; nb < 4; ++nb) {
        const int s = s0 + nb * 16 + l15;
        #pragma unroll
        for (int r = 0; r < 4; ++r)
          lsum[nb] += (tbase + r >= s) ? EXP2(sacc[nb][r]) : 0.f;
      }
    } else {
      #pragma unroll
      for (int nb = 0; nb < 4; ++nb)
        #pragma unroll
        for (int r = 0; r < 4; ++r) lsum[nb] += EXP2(sacc[nb][r]);
    }
    __syncthreads();
  }
  #pragma unroll
  for (int nb = 0; nb < 4; ++nb) {
    lsum[nb] += __shfl_xor(lsum[nb], 16);
    lsum[nb] += __shfl_xor(lsum[nb], 32);
  }
  if (lane < 16) {
    #pragma unroll
    for (int nb = 0; nb < 4; ++nb) red[wv][nb * 16 + lane] = lsum[nb];
  }
  __syncthreads();
  if (tid < 64) {
    const float L = red[0][tid] + red[1][tid] + red[2][tid] + red[3][tid];
    lg[(size_t)bh * T_ + s0 + tid] = -__log2f(L);
  }
}

// ---------------------------------------------------------------------------
// Output. grid (H, B, NT) = 1024 blocks, jt = 31-z heavy-first. K/Vt/lg
// DOUBLE-BUFFERED dma8 (42.7 KB LDS -> 3 blocks/CU). Quadrant ownership:
// wave (th,sh) owns 32t x 32s. U wave-private. Diagonal (th=0,sh=1) skipped.
// End: O partials reduced through retired k_s. [round-1 form + setprio(T5)]
// ---------------------------------------------------------------------------
__global__ __launch_bounds__(256) void out_kernel(
    const unsigned short* __restrict__ q, const unsigned short* __restrict__ k,
    const unsigned short* __restrict__ vt, const float* __restrict__ lg,
    float* __restrict__ out)
{
  __shared__ __align__(16) unsigned short k_s[2][64 * 64];    // 16 KB (reused as O-scratch)
  __shared__ __align__(16) unsigned short vt_s[2][64 * 64];   // 16 KB
  __shared__ __align__(16) unsigned short u_s[4][32][40];     // 10 KB wave-private U quadrants
  __shared__ float lg_sh[2][64];
  const int tid = threadIdx.x;
  const int lane = tid & 63, wv = tid >> 6;
  const int l15 = lane & 15, quad = lane >> 4;
  const int th = wv >> 1, sh = wv & 1;           // wave's t-half / s-half
  const int h = blockIdx.x, b = blockIdx.y, jt = 31 - blockIdx.z;
  const int bh = b * H_ + h;
  const int t0 = jt * 64;
  const unsigned short* kbase = k + (size_t)bh * T_ * 64;
  const unsigned short* vbase = vt + (size_t)bh * D_ * T_;
  const float* lgbase = lg + (size_t)bh * T_;

  // one-time Q B-frags: this wave's 32 t-cols (2 n-tiles x 2 k-steps)
  bf16x8 qf[2][2];
  #pragma unroll
  for (int nt = 0; nt < 2; ++nt) {
    const unsigned short* qrow = q + (size_t)(bh * T_ + t0 + th * 32 + nt * 16 + l15) * 64;
    qf[nt][0] = *(const bf16x8*)(qrow + quad * 8);
    qf[nt][1] = *(const bf16x8*)(qrow + 32 + quad * 8);
  }

  // stage unit 0 into slot 0
  #pragma unroll
  for (int pp = 0; pp < 2; ++pp) {
    const int br = wv * 16 + pp * 8;
    dma8(kbase + (size_t)br * 64, 64, &k_s[0][br * 64], lane);
    dma8(vbase + (size_t)br * T_, T_, &vt_s[0][br * 64], lane);
  }
  if (tid < 64) lg_sh[0][tid] = lgbase[tid];
  __syncthreads();

  f32x4 oacc[4][2];                              // [d-tile][t-tile of own half]
  #pragma unroll
  for (int mb = 0; mb < 4; ++mb)
    #pragma unroll
    for (int nt = 0; nt < 2; ++nt) oacc[mb][nt] = (f32x4){0.f, 0.f, 0.f, 0.f};

  for (int st = 0; st <= jt; ++st) {
    const int bi = st & 1;
    if (st < jt) {                               // prefetch next unit
      const int s1 = (st + 1) * 64;
      #pragma unroll
      for (int pp = 0; pp < 2; ++pp) {
        const int br = wv * 16 + pp * 8;
        dma8(kbase + (size_t)(s1 + br) * 64, 64, &k_s[bi ^ 1][br * 64], lane);
        dma8(vbase + (size_t)br * T_ + s1, T_, &vt_s[bi ^ 1][br * 64], lane);
      }
      if (tid < 64) lg_sh[bi ^ 1][tid] = lgbase[s1 + tid];
    }
    const unsigned short* ks = k_s[bi];
    const unsigned short* vs = vt_s[bi];
    const float* lgb = lg_sh[bi];

    const bool dead = (st == jt) && (th == 0) && (sh == 1);  // fully-masked quadrant
    if (!dead) {
      // S^T quadrant: A = K rows (own s-half), B = Q (reg); C init = lg[s]
      f32x4 sacc[2][2];
      #pragma unroll
      for (int mb = 0; mb < 2; ++mb) {
        float lg4[4];
        *(float4*)lg4 = *(const float4*)&lgb[sh * 32 + mb * 16 + quad * 4];
        #pragma unroll
        for (int nt = 0; nt < 2; ++nt)
          sacc[mb][nt] = (f32x4){lg4[0], lg4[1], lg4[2], lg4[3]};
      }
      __builtin_amdgcn_s_setprio(1);
      #pragma unroll
      for (int mb = 0; mb < 2; ++mb) {
        bf16x8 ka0 = frag(ks, sh * 32 + mb * 16 + l15, quad);
        bf16x8 ka1 = frag(ks, sh * 32 + mb * 16 + l15, 4 + quad);
        #pragma unroll
        for (int nt = 0; nt < 2; ++nt) {
          sacc[mb][nt] = __builtin_amdgcn_mfma_f32_16x16x32_bf16(ka0, qf[nt][0], sacc[mb][nt], 0, 0, 0);
          sacc[mb][nt] = __builtin_amdgcn_mfma_f32_16x16x32_bf16(ka1, qf[nt][1], sacc[mb][nt], 0, 0, 0);
        }
      }
      __builtin_amdgcn_s_setprio(0);
      // U = exp2(S' + lg[s]); diagonal quadrants (th==sh) masked elementwise
      const bool diagmask = (st == jt) && (th == sh);
      #pragma unroll
      for (int mb = 0; mb < 2; ++mb)
        #pragma unroll
        for (int nt = 0; nt < 2; ++nt) {
          float uu[4] = { EXP2(sacc[mb][nt][0]), EXP2(sacc[mb][nt][1]),
                          EXP2(sacc[mb][nt][2]), EXP2(sacc[mb][nt][3]) };
          if (diagmask) {
            const int tl = nt * 16 + l15, sl = mb * 16 + quad * 4;
            #pragma unroll
            for (int r = 0; r < 4; ++r) if (tl < sl + r) uu[r] = 0.f;
          }
          *(uint2*)(&u_s[wv][nt * 16 + l15][mb * 16 + quad * 4]) =
              make_uint2(pk2bf(uu[0], uu[1]), pk2bf(uu[2], uu[3]));
        }
      // O^T partial += Vt[:, own s-half] . U^T — same-wave LDS dep, K-dim=32
      __builtin_amdgcn_s_setprio(1);
      #pragma unroll
      for (int nt = 0; nt < 2; ++nt) {
        bf16x8 ua = *(const bf16x8*)(&u_s[wv][nt * 16 + l15][quad * 8]);
        #pragma unroll
        for (int mb = 0; mb < 4; ++mb)
          oacc[mb][nt] = __builtin_amdgcn_mfma_f32_16x16x32_bf16(
              frag(vs, mb * 16 + l15, sh * 4 + quad), ua, oacc[mb][nt], 0, 0, 0);
      }
      __builtin_amdgcn_s_setprio(0);
    }
    __syncthreads();   // waves done with slot bi; prefetch into bi^1 drained
  }

  // cross-wave reduce over s-halves: sh=1 writes partials to retired k_s (fp32)
  float* scr = (float*)k_s;                      // 16 KB = 2 th x 8 acc x 64 lanes x 16B
  if (sh == 1) {
    #pragma unroll
    for (int mb = 0; mb < 4; ++mb)
      #pragma unroll
      for (int nt = 0; nt < 2; ++nt) {
        float o4[4] = { oacc[mb][nt][0], oacc[mb][nt][1], oacc[mb][nt][2], oacc[mb][nt][3] };
        *(float4*)&scr[((th * 8 + mb * 2 + nt) * 64 + lane) * 4] = *(const float4*)o4;
      }
  }
  __syncthreads();
  if (sh == 0) {
    #pragma unroll
    for (int nt = 0; nt < 2; ++nt) {
      float* orow = out + ((size_t)(b * T_ + t0 + th * 32 + nt * 16 + l15)) * (H_ * D_) + h * D_;
      #pragma unroll
      for (int mb = 0; mb < 4; ++mb) {
        float4 p = *(const float4*)&scr[((th * 8 + mb * 2 + nt) * 64 + lane) * 4];
        float o4[4] = { oacc[mb][nt][0] + p.x, oacc[mb][nt][1] + p.y,
                        oacc[mb][nt][2] + p.z, oacc[mb][nt][3] + p.w };
        *(float4*)(orow + mb * 16 + quad * 4) = *(const float4*)o4;
      }
    }
  }
}

extern "C" void kernel_launch(void* const* d_in, const int* in_sizes, int n_in,
                              void* d_out, int out_size, void* d_ws, size_t ws_size,
                              hipStream_t stream) {
  const float* in = (const float*)d_in[0];
  const float* kw = (const float*)d_in[1];
  const float* kb = (const float*)d_in[2];
  const float* qw = (const float*)d_in[3];
  const float* qb = (const float*)d_in[4];
  const float* vw = (const float*)d_in[5];
  const float* vb = (const float*)d_in[6];
  float* out = (float*)d_out;

  // ws (bf16): in16 | qwt|kwt|vwt (H,D,E) | q16|k16 (B,H,T,D) | vt (B,H,D,T) | lg fp32
  unsigned short* p = (unsigned short*)d_ws;
  const size_t inz = (size_t)B_ * T_ * E_;
  const size_t wz  = (size_t)H_ * D_ * E_;
  const size_t qz  = (size_t)B_ * H_ * T_ * D_;
  unsigned short* in16 = p;            p += inz;
  unsigned short* qwt  = p;            p += wz;
  unsigned short* kwt  = p;            p += wz;
  unsigned short* vwt  = p;            p += wz;
  unsigned short* q16  = p;            p += qz;
  unsigned short* k16  = p;            p += qz;
  unsigned short* vtb  = p;            p += qz;
  float* lgbuf = (float*)p;

  dim3 blk(256);
  pack_kernel <<<dim3(2048 + 768), blk, 0, stream>>>(in, in16, qw, kw, vw, qwt, kwt, vwt);
  proj_kernel <<<dim3(T_ / 128, H_, B_), blk, 0, stream>>>(in16, qwt, kwt, vwt,
                                                           qb, kb, vb, q16, k16, vtb);
  stats_kernel<<<dim3(H_, B_, NT_), blk, 0, stream>>>(q16, k16, lgbuf);
  out_kernel  <<<dim3(H_, B_, NT_), blk, 0, stream>>>(q16, k16, vtb, lgbuf, out);
}

// Round 7
// 169.121 us; speedup vs baseline: 1.4576x; 1.0176x over previous
//
#include <hip/hip_runtime.h>
#include <hip/hip_bf16.h>
#include <math.h>

#define B_ 2
#define T_ 2048
#define E_ 1024
#define H_ 16
#define D_ 64
#define NT_ 32          // T/64 tiles
#define QSCALE 0.180336880f   // 0.125 * log2(e): folded into q so exp(S/8) = exp2(S')

typedef __attribute__((ext_vector_type(8))) short bf16x8;   // MFMA A/B frag (4 VGPRs)
typedef __attribute__((ext_vector_type(4))) float f32x4;    // MFMA C/D frag

#if __has_builtin(__builtin_amdgcn_exp2f)
#define EXP2(x) __builtin_amdgcn_exp2f(x)
#else
#define EXP2(x) exp2f(x)
#endif

__device__ __forceinline__ unsigned short f2bf(float x) {   // RNE fp32->bf16
  union { float f; unsigned u; } v; v.f = x;
  unsigned r = v.u + 0x7FFFu + ((v.u >> 16) & 1u);
  return (unsigned short)(r >> 16);
}
__device__ __forceinline__ unsigned pk2bf(float a, float b) {  // low=a, high=b (HW cvt_pk)
  __hip_bfloat162 h = __float22bfloat162_rn(make_float2(a, b));
  union { __hip_bfloat162 h; unsigned u; } c; c.h = h; return c.u;
}

// Async global->LDS: one wave-instr stages 8 rows x 64 bf16 (8 blocks of 16B),
// XOR-swizzled: LDS slot (row, bs) holds global block bs ^ (row&7).
__device__ __forceinline__ void dma8(const unsigned short* g, int gstride,
                                     unsigned short* l, int lane)
{
  const int r = lane >> 3, bg = (lane & 7) ^ (r & 7);
  __builtin_amdgcn_global_load_lds(
      (const __attribute__((address_space(1))) void*)(g + (size_t)r * gstride + bg * 8),
      (__attribute__((address_space(3))) void*)l, 16, 0, 0);
}
__device__ __forceinline__ bf16x8 frag(const unsigned short* tile, int row, int g) {
  return *(const bf16x8*)(tile + row * 64 + (((g ^ row) & 7) << 3));
}

// ---------------------------------------------------------------------------
// fused pack: blocks [0,2048) = input fp32->bf16; [2048,2816) = weight
// transpose (H,E,D) fp32 -> (H,D,E) bf16.
// ---------------------------------------------------------------------------
__global__ __launch_bounds__(256) void pack_kernel(
    const float* __restrict__ in, unsigned short* __restrict__ o16,
    const float* __restrict__ qw, const float* __restrict__ kw, const float* __restrict__ vw,
    unsigned short* __restrict__ qwt, unsigned short* __restrict__ kwt,
    unsigned short* __restrict__ vwt)
{
  __shared__ float s[64][65];
  const int tid = threadIdx.x;
  if (blockIdx.x < 2048) {                       // input pack
    const size_t i = ((size_t)blockIdx.x * 256 + tid) * 8;
    float4 f0 = *(const float4*)(in + i);
    float4 f1 = *(const float4*)(in + i + 4);
    unsigned u[4] = { pk2bf(f0.x, f0.y), pk2bf(f0.z, f0.w),
                      pk2bf(f1.x, f1.y), pk2bf(f1.z, f1.w) };
    *(bf16x8*)(o16 + i) = *(const bf16x8*)u;
    return;
  }
  const int i = blockIdx.x - 2048;
  const int e0 = (i & 15) * 64, h = (i >> 4) & 15, z = i >> 8;
  const float* w = (z == 0) ? qw : (z == 1) ? kw : vw;
  unsigned short* o = (z == 0) ? qwt : (z == 1) ? kwt : vwt;
  {
    const int r = tid >> 2;
    #pragma unroll
    for (int p = 0; p < 4; ++p) {
      const int c = (tid & 3) * 4 + p * 16;
      float4 f = *(const float4*)(w + ((size_t)(h * E_ + e0 + r)) * D_ + c);
      s[r][c] = f.x; s[r][c+1] = f.y; s[r][c+2] = f.z; s[r][c+3] = f.w;
    }
  }
  __syncthreads();
  {
    const int d = tid >> 2, ec = (tid & 3) * 16;
    unsigned short tmp[16];
    #pragma unroll
    for (int j = 0; j < 16; ++j) tmp[j] = f2bf(s[ec + j][d]);
    unsigned short* dst = o + ((size_t)(h * D_ + d)) * E_ + e0 + ec;
    *(bf16x8*)(dst)     = *(const bf16x8*)&tmp[0];
    *(bf16x8*)(dst + 8) = *(const bf16x8*)&tmp[8];
  }
}

// ---------------------------------------------------------------------------
// QKV projection. grid (T/128, H, B) = 512. Wave retile: wave wv owns
// n-blocks {q:wv, k:wv, v:wv} (16-wide each, compile-time x) for ALL 128 t —
// 22 LDS frag reads/wave/iter, 48 MFMA. BK=64, dbuf dma8 staging.
// [round-1 form: best verified total 169.9 us — do not perturb]
// ---------------------------------------------------------------------------
__global__ __launch_bounds__(256) void proj_kernel(
    const unsigned short* __restrict__ in16,
    const unsigned short* __restrict__ qwt, const unsigned short* __restrict__ kwt,
    const unsigned short* __restrict__ vwt,
    const float* __restrict__ qb, const float* __restrict__ kb, const float* __restrict__ vb,
    unsigned short* __restrict__ qo, unsigned short* __restrict__ ko,
    unsigned short* __restrict__ vt)
{
  __shared__ __align__(16) unsigned short in_s[2][128 * 64];   // 32 KB
  __shared__ __align__(16) unsigned short w_s[2][3 * 64 * 64]; // 48 KB (flat rows: x*64+d)
  const int tid = threadIdx.x;
  const int lane = tid & 63, wv = tid >> 6;
  const int l15 = lane & 15, quad = lane >> 4;
  const int t0 = blockIdx.x * 128, h = blockIdx.y, b = blockIdx.z;
  const int bh = b * H_ + h;
  const unsigned short* wts[3] = { qwt, kwt, vwt };

  f32x4 acc[3][8];
  #pragma unroll
  for (int x = 0; x < 3; ++x)
    #pragma unroll
    for (int tb = 0; tb < 8; ++tb) acc[x][tb] = (f32x4){0.f, 0.f, 0.f, 0.f};

#define PROJ_STAGE(e0_, bi_)                                                      \
  {                                                                               \
    const unsigned short* gin = in16 + ((size_t)(b * T_ + t0)) * E_ + (e0_);      \
    _Pragma("unroll")                                                             \
    for (int p = 0; p < 4; ++p) {                                                 \
      const int br = wv * 32 + p * 8;                                             \
      dma8(gin + (size_t)br * E_, E_, &in_s[bi_][br * 64], lane);                 \
    }                                                                             \
    _Pragma("unroll")                                                             \
    for (int j = 0; j < 6; ++j) {                                                 \
      const int idx = wv * 6 + j;                                                 \
      const int x = idx >> 3, br = (idx & 7) * 8;                                 \
      dma8(wts[x] + ((size_t)(h * D_ + br)) * E_ + (e0_), E_,                     \
           &w_s[bi_][x * 4096 + br * 64], lane);                                  \
    }                                                                             \
  }

  PROJ_STAGE(0, 0);
  __syncthreads();
  for (int e = 0; e < 16; ++e) {
    const int bi = e & 1;
    if (e < 15) PROJ_STAGE((e + 1) * 64, bi ^ 1);
    const unsigned short* is = in_s[bi];
    const unsigned short* ws = w_s[bi];
    #pragma unroll
    for (int kk = 0; kk < 2; ++kk) {
      const int g0 = kk * 4 + quad;
      bf16x8 bfr[3];
      #pragma unroll
      for (int x = 0; x < 3; ++x)
        bfr[x] = frag(ws, x * 64 + wv * 16 + l15, g0);
      bf16x8 afr[8];
      #pragma unroll
      for (int tb = 0; tb < 8; ++tb)
        afr[tb] = frag(is, tb * 16 + l15, g0);
      #pragma unroll
      for (int tb = 0; tb < 8; ++tb) {
        // q,k: A=w (m=d), B=in (n=t) -> C col=t; v: A=in (m=t), B=w -> C col=d
        acc[0][tb] = __builtin_amdgcn_mfma_f32_16x16x32_bf16(bfr[0], afr[tb], acc[0][tb], 0, 0, 0);
        acc[1][tb] = __builtin_amdgcn_mfma_f32_16x16x32_bf16(bfr[1], afr[tb], acc[1][tb], 0, 0, 0);
        acc[2][tb] = __builtin_amdgcn_mfma_f32_16x16x32_bf16(afr[tb], bfr[2], acc[2][tb], 0, 0, 0);
      }
    }
    __syncthreads();
  }
#undef PROJ_STAGE

  const size_t obase = (size_t)bh * T_;
  // q (scaled) and k: lane t = tb*16+l15, 4 consecutive d -> ushort4 stores
  #pragma unroll
  for (int x = 0; x < 2; ++x) {
    const float scl = (x == 0) ? QSCALE : 1.0f;
    const float* bias = (x == 0) ? qb : kb;
    unsigned short* outp = (x == 0) ? qo : ko;
    float bias4[4];
    *(float4*)bias4 = *(const float4*)&bias[h * D_ + wv * 16 + quad * 4];
    #pragma unroll
    for (int tb = 0; tb < 8; ++tb) {
      const int t = t0 + tb * 16 + l15;
      unsigned short pk[4];
      #pragma unroll
      for (int r = 0; r < 4; ++r) pk[r] = f2bf((acc[x][tb][r] + bias4[r]) * scl);
      *(ushort4*)(outp + (obase + t) * D_ + wv * 16 + quad * 4) = *(const ushort4*)pk;
    }
  }
  // v: transposed [d][t] — lane d = wv*16+l15, 4 consecutive t -> ushort4
  {
    const int d = wv * 16 + l15;
    const float bvv = vb[h * D_ + d];
    #pragma unroll
    for (int tb = 0; tb < 8; ++tb) {
      const int t = t0 + tb * 16 + quad * 4;
      unsigned short pk[4];
      #pragma unroll
      for (int r = 0; r < 4; ++r) pk[r] = f2bf(acc[2][tb][r] + bvv);
      *(ushort4*)(vt + ((size_t)(bh * D_ + d)) * T_ + t) = *(const ushort4*)pk;
    }
  }
}

// ---------------------------------------------------------------------------
// Column softmax: lg[s] = -log2( sum_t exp2(S'[t,s]) ). grid (H, B, NT) =
// 1024 blocks; sa=0 (heaviest) first. K B-frags reg-resident.
// BARRIER-FREE main loop: wave wv stages ONLY rows [wv*16, wv*16+16) of each
// Q tile (dma8 br = wv*16+pp*8) and reads ONLY those rows (frag row =
// wv*16+l15) -> zero cross-wave LDS sharing. Tri-buffered q_s[3] (24 KB),
// per-wave 2-deep pipeline paced by own counted s_waitcnt vmcnt(2): stage(tt)
// retired, stage(tt+1) in flight, stage(tt+2) issued after frag reads.
// Removes the per-iter __syncthreads vmcnt(0)+lgkmcnt(0) drain that exposed
// ~500cy staging latency to all 4 waves in lockstep. WAR safe: stage(tt+2)
// overwrites the slot read at iter tt-1, whose ds_reads completed before
// iter tt-1's MFMAs. One barrier remains before the cross-wave red[] reduce.
// ---------------------------------------------------------------------------
__global__ __launch_bounds__(256) void stats_kernel(
    const unsigned short* __restrict__ q, const unsigned short* __restrict__ k,
    float* __restrict__ lg)
{
  __shared__ __align__(16) unsigned short q_s[3][64 * 64];   // 24 KB tri-buffer
  __shared__ float red[4][64];
  const int tid = threadIdx.x;
  const int lane = tid & 63, wv = tid >> 6;
  const int l15 = lane & 15, quad = lane >> 4;
  const int h = blockIdx.x, b = blockIdx.y, sa = blockIdx.z;
  const int bh = b * H_ + h;
  const int s0 = sa * 64;
  const unsigned short* qbase = q + (size_t)bh * T_ * 64;

  bf16x8 kf[4][2];                               // reg-resident K B-frags (one-time)
  #pragma unroll
  for (int nb = 0; nb < 4; ++nb)
    #pragma unroll
    for (int kk = 0; kk < 2; ++kk)
      kf[nb][kk] = *(const bf16x8*)(k + ((size_t)(bh * T_ + s0 + nb * 16 + l15)) * 64
                                      + kk * 32 + quad * 8);

#define ST_STAGE(tt_, slot_)                                                 \
  { _Pragma("unroll")                                                        \
    for (int pp = 0; pp < 2; ++pp) {                                         \
      const int br = wv * 16 + pp * 8;                                       \
      dma8(qbase + (size_t)((tt_) * 64 + br) * 64, 64, &q_s[slot_][br * 64], lane); \
    } }

  ST_STAGE(sa, 0);
  if (sa + 1 < NT_) ST_STAGE(sa + 1, 1);

  float lsum[4] = {0.f, 0.f, 0.f, 0.f};

  for (int tt = sa; tt < NT_; ++tt) {
    const int i = tt - sa;
    // own stage(tt) retired; stage(tt+1) (2 ops) may stay in flight
    if (tt + 1 < NT_) asm volatile("s_waitcnt vmcnt(2)" ::: "memory");
    else              asm volatile("s_waitcnt vmcnt(0)" ::: "memory");
    __builtin_amdgcn_sched_barrier(0);           // don't hoist reads above the wait

    const unsigned short* qs = q_s[i % 3];
    bf16x8 a0 = frag(qs, wv * 16 + l15, quad);
    bf16x8 a1 = frag(qs, wv * 16 + l15, 4 + quad);
    if (tt + 2 < NT_) ST_STAGE(tt + 2, (i + 2) % 3);

    f32x4 sacc[4];
    #pragma unroll
    for (int nb = 0; nb < 4; ++nb) sacc[nb] = (f32x4){0.f, 0.f, 0.f, 0.f};
    #pragma unroll
    for (int nb = 0; nb < 4; ++nb) {
      sacc[nb] = __builtin_amdgcn_mfma_f32_16x16x32_bf16(a0, kf[nb][0], sacc[nb], 0, 0, 0);
      sacc[nb] = __builtin_amdgcn_mfma_f32_16x16x32_bf16(a1, kf[nb][1], sacc[nb], 0, 0, 0);
    }
    if (tt == sa) {                              // diagonal tile: causal mask
      const int tbase = tt * 64 + wv * 16 + quad * 4;
      #pragma unroll
      for (int nb = 0; nb < 4; ++nb) {
        const int s = s0 + nb * 16 + l15;
        #pragma unroll
        for (int r = 0; r < 4; ++r)
          lsum[nb] += (tbase + r >= s) ? EXP2(sacc[nb][r]) : 0.f;
      }
    } else {
      #pragma unroll
      for (int nb = 0; nb < 4; ++nb)
        #pragma unroll
        for (int r = 0; r < 4; ++r) lsum[nb] += EXP2(sacc[nb][r]);
    }
  }
#undef ST_STAGE
  #pragma unroll
  for (int nb = 0; nb < 4; ++nb) {
    lsum[nb] += __shfl_xor(lsum[nb], 16);
    lsum[nb] += __shfl_xor(lsum[nb], 32);
  }
  if (lane < 16) {
    #pragma unroll
    for (int nb = 0; nb < 4; ++nb) red[wv][nb * 16 + lane] = lsum[nb];
  }
  __syncthreads();                               // only cross-wave sync point
  if (tid < 64) {
    const float L = red[0][tid] + red[1][tid] + red[2][tid] + red[3][tid];
    lg[(size_t)bh * T_ + s0 + tid] = -__log2f(L);
  }
}

// ---------------------------------------------------------------------------
// Output. grid (H, B, NT) = 1024 blocks, jt = 31-z heavy-first. K/Vt/lg
// DOUBLE-BUFFERED dma8 (42.7 KB LDS -> 3 blocks/CU). Quadrant ownership:
// wave (th,sh) owns 32t x 32s. U wave-private. Diagonal (th=0,sh=1) skipped.
// End: O partials reduced through retired k_s. [round-1 form]
// ---------------------------------------------------------------------------
__global__ __launch_bounds__(256) void out_kernel(
    const unsigned short* __restrict__ q, const unsigned short* __restrict__ k,
    const unsigned short* __restrict__ vt, const float* __restrict__ lg,
    float* __restrict__ out)
{
  __shared__ __align__(16) unsigned short k_s[2][64 * 64];    // 16 KB (reused as O-scratch)
  __shared__ __align__(16) unsigned short vt_s[2][64 * 64];   // 16 KB
  __shared__ __align__(16) unsigned short u_s[4][32][40];     // 10 KB wave-private U quadrants
  __shared__ float lg_sh[2][64];
  const int tid = threadIdx.x;
  const int lane = tid & 63, wv = tid >> 6;
  const int l15 = lane & 15, quad = lane >> 4;
  const int th = wv >> 1, sh = wv & 1;           // wave's t-half / s-half
  const int h = blockIdx.x, b = blockIdx.y, jt = 31 - blockIdx.z;
  const int bh = b * H_ + h;
  const int t0 = jt * 64;
  const unsigned short* kbase = k + (size_t)bh * T_ * 64;
  const unsigned short* vbase = vt + (size_t)bh * D_ * T_;
  const float* lgbase = lg + (size_t)bh * T_;

  // one-time Q B-frags: this wave's 32 t-cols (2 n-tiles x 2 k-steps)
  bf16x8 qf[2][2];
  #pragma unroll
  for (int nt = 0; nt < 2; ++nt) {
    const unsigned short* qrow = q + (size_t)(bh * T_ + t0 + th * 32 + nt * 16 + l15) * 64;
    qf[nt][0] = *(const bf16x8*)(qrow + quad * 8);
    qf[nt][1] = *(const bf16x8*)(qrow + 32 + quad * 8);
  }

  // stage unit 0 into slot 0
  #pragma unroll
  for (int pp = 0; pp < 2; ++pp) {
    const int br = wv * 16 + pp * 8;
    dma8(kbase + (size_t)br * 64, 64, &k_s[0][br * 64], lane);
    dma8(vbase + (size_t)br * T_, T_, &vt_s[0][br * 64], lane);
  }
  if (tid < 64) lg_sh[0][tid] = lgbase[tid];
  __syncthreads();

  f32x4 oacc[4][2];                              // [d-tile][t-tile of own half]
  #pragma unroll
  for (int mb = 0; mb < 4; ++mb)
    #pragma unroll
    for (int nt = 0; nt < 2; ++nt) oacc[mb][nt] = (f32x4){0.f, 0.f, 0.f, 0.f};

  for (int st = 0; st <= jt; ++st) {
    const int bi = st & 1;
    if (st < jt) {                               // prefetch next unit
      const int s1 = (st + 1) * 64;
      #pragma unroll
      for (int pp = 0; pp < 2; ++pp) {
        const int br = wv * 16 + pp * 8;
        dma8(kbase + (size_t)(s1 + br) * 64, 64, &k_s[bi ^ 1][br * 64], lane);
        dma8(vbase + (size_t)br * T_ + s1, T_, &vt_s[bi ^ 1][br * 64], lane);
      }
      if (tid < 64) lg_sh[bi ^ 1][tid] = lgbase[s1 + tid];
    }
    const unsigned short* ks = k_s[bi];
    const unsigned short* vs = vt_s[bi];
    const float* lgb = lg_sh[bi];

    const bool dead = (st == jt) && (th == 0) && (sh == 1);  // fully-masked quadrant
    if (!dead) {
      // S^T quadrant: A = K rows (own s-half), B = Q (reg); C init = lg[s]
      f32x4 sacc[2][2];
      #pragma unroll
      for (int mb = 0; mb < 2; ++mb) {
        float lg4[4];
        *(float4*)lg4 = *(const float4*)&lgb[sh * 32 + mb * 16 + quad * 4];
        #pragma unroll
        for (int nt = 0; nt < 2; ++nt)
          sacc[mb][nt] = (f32x4){lg4[0], lg4[1], lg4[2], lg4[3]};
      }
      #pragma unroll
      for (int mb = 0; mb < 2; ++mb) {
        bf16x8 ka0 = frag(ks, sh * 32 + mb * 16 + l15, quad);
        bf16x8 ka1 = frag(ks, sh * 32 + mb * 16 + l15, 4 + quad);
        #pragma unroll
        for (int nt = 0; nt < 2; ++nt) {
          sacc[mb][nt] = __builtin_amdgcn_mfma_f32_16x16x32_bf16(ka0, qf[nt][0], sacc[mb][nt], 0, 0, 0);
          sacc[mb][nt] = __builtin_amdgcn_mfma_f32_16x16x32_bf16(ka1, qf[nt][1], sacc[mb][nt], 0, 0, 0);
        }
      }
      // U = exp2(S' + lg[s]); diagonal quadrants (th==sh) masked elementwise
      const bool diagmask = (st == jt) && (th == sh);
      #pragma unroll
      for (int mb = 0; mb < 2; ++mb)
        #pragma unroll
        for (int nt = 0; nt < 2; ++nt) {
          float uu[4] = { EXP2(sacc[mb][nt][0]), EXP2(sacc[mb][nt][1]),
                          EXP2(sacc[mb][nt][2]), EXP2(sacc[mb][nt][3]) };
          if (diagmask) {
            const int tl = nt * 16 + l15, sl = mb * 16 + quad * 4;
            #pragma unroll
            for (int r = 0; r < 4; ++r) if (tl < sl + r) uu[r] = 0.f;
          }
          *(uint2*)(&u_s[wv][nt * 16 + l15][mb * 16 + quad * 4]) =
              make_uint2(pk2bf(uu[0], uu[1]), pk2bf(uu[2], uu[3]));
        }
      // O^T partial += Vt[:, own s-half] . U^T — same-wave LDS dep, K-dim=32
      #pragma unroll
      for (int nt = 0; nt < 2; ++nt) {
        bf16x8 ua = *(const bf16x8*)(&u_s[wv][nt * 16 + l15][quad * 8]);
        #pragma unroll
        for (int mb = 0; mb < 4; ++mb)
          oacc[mb][nt] = __builtin_amdgcn_mfma_f32_16x16x32_bf16(
              frag(vs, mb * 16 + l15, sh * 4 + quad), ua, oacc[mb][nt], 0, 0, 0);
      }
    }
    __syncthreads();   // waves done with slot bi; prefetch into bi^1 drained
  }

  // cross-wave reduce over s-halves: sh=1 writes partials to retired k_s (fp32)
  float* scr = (float*)k_s;                      // 16 KB = 2 th x 8 acc x 64 lanes x 16B
  if (sh == 1) {
    #pragma unroll
    for (int mb = 0; mb < 4; ++mb)
      #pragma unroll
      for (int nt = 0; nt < 2; ++nt) {
        float o4[4] = { oacc[mb][nt][0], oacc[mb][nt][1], oacc[mb][nt][2], oacc[mb][nt][3] };
        *(float4*)&scr[((th * 8 + mb * 2 + nt) * 64 + lane) * 4] = *(const float4*)o4;
      }
  }
  __syncthreads();
  if (sh == 0) {
    #pragma unroll
    for (int nt = 0; nt < 2; ++nt) {
      float* orow = out + ((size_t)(b * T_ + t0 + th * 32 + nt * 16 + l15)) * (H_ * D_) + h * D_;
      #pragma unroll
      for (int mb = 0; mb < 4; ++mb) {
        float4 p = *(const float4*)&scr[((th * 8 + mb * 2 + nt) * 64 + lane) * 4];
        float o4[4] = { oacc[mb][nt][0] + p.x, oacc[mb][nt][1] + p.y,
                        oacc[mb][nt][2] + p.z, oacc[mb][nt][3] + p.w };
        *(float4*)(orow + mb * 16 + quad * 4) = *(const float4*)o4;
      }
    }
  }
}

extern "C" void kernel_launch(void* const* d_in, const int* in_sizes, int n_in,
                              void* d_out, int out_size, void* d_ws, size_t ws_size,
                              hipStream_t stream) {
  const float* in = (const float*)d_in[0];
  const float* kw = (const float*)d_in[1];
  const float* kb = (const float*)d_in[2];
  const float* qw = (const float*)d_in[3];
  const float* qb = (const float*)d_in[4];
  const float* vw = (const float*)d_in[5];
  const float* vb = (const float*)d_in[6];
  float* out = (float*)d_out;

  // ws (bf16): in16 | qwt|kwt|vwt (H,D,E) | q16|k16 (B,H,T,D) | vt (B,H,D,T) | lg fp32
  unsigned short* p = (unsigned short*)d_ws;
  const size_t inz = (size_t)B_ * T_ * E_;
  const size_t wz  = (size_t)H_ * D_ * E_;
  const size_t qz  = (size_t)B_ * H_ * T_ * D_;
  unsigned short* in16 = p;            p += inz;
  unsigned short* qwt  = p;            p += wz;
  unsigned short* kwt  = p;            p += wz;
  unsigned short* vwt  = p;            p += wz;
  unsigned short* q16  = p;            p += qz;
  unsigned short* k16  = p;            p += qz;
  unsigned short* vtb  = p;            p += qz;
  float* lgbuf = (float*)p;

  dim3 blk(256);
  pack_kernel <<<dim3(2048 + 768), blk, 0, stream>>>(in, in16, qw, kw, vw, qwt, kwt, vwt);
  proj_kernel <<<dim3(T_ / 128, H_, B_), blk, 0, stream>>>(in16, qwt, kwt, vwt,
                                                           qb, kb, vb, q16, k16, vtb);
  stats_kernel<<<dim3(H_, B_, NT_), blk, 0, stream>>>(q16, k16, lgbuf);
  out_kernel  <<<dim3(H_, B_, NT_), blk, 0, stream>>>(q16, k16, vtb, lgbuf, out);
}

// Round 8
// 168.224 us; speedup vs baseline: 1.4654x; 1.0053x over previous
//
#include <hip/hip_runtime.h>
#include <hip/hip_bf16.h>
#include <math.h>

#define B_ 2
#define T_ 2048
#define E_ 1024
#define H_ 16
#define D_ 64
#define NT_ 32          // T/64 tiles
#define QSCALE 0.180336880f   // 0.125 * log2(e): folded into q so exp(S/8) = exp2(S')

typedef __attribute__((ext_vector_type(8))) short bf16x8;   // MFMA A/B frag (4 VGPRs)
typedef __attribute__((ext_vector_type(4))) float f32x4;    // MFMA C/D frag

#if __has_builtin(__builtin_amdgcn_exp2f)
#define EXP2(x) __builtin_amdgcn_exp2f(x)
#else
#define EXP2(x) exp2f(x)
#endif

__device__ __forceinline__ unsigned short f2bf(float x) {   // RNE fp32->bf16
  union { float f; unsigned u; } v; v.f = x;
  unsigned r = v.u + 0x7FFFu + ((v.u >> 16) & 1u);
  return (unsigned short)(r >> 16);
}
__device__ __forceinline__ unsigned pk2bf(float a, float b) {  // low=a, high=b (HW cvt_pk)
  __hip_bfloat162 h = __float22bfloat162_rn(make_float2(a, b));
  union { __hip_bfloat162 h; unsigned u; } c; c.h = h; return c.u;
}

// Async global->LDS: one wave-instr stages 8 rows x 64 bf16 (8 blocks of 16B),
// XOR-swizzled: LDS slot (row, bs) holds global block bs ^ (row&7).
__device__ __forceinline__ void dma8(const unsigned short* g, int gstride,
                                     unsigned short* l, int lane)
{
  const int r = lane >> 3, bg = (lane & 7) ^ (r & 7);
  __builtin_amdgcn_global_load_lds(
      (const __attribute__((address_space(1))) void*)(g + (size_t)r * gstride + bg * 8),
      (__attribute__((address_space(3))) void*)l, 16, 0, 0);
}
__device__ __forceinline__ bf16x8 frag(const unsigned short* tile, int row, int g) {
  return *(const bf16x8*)(tile + row * 64 + (((g ^ row) & 7) << 3));
}

// ---------------------------------------------------------------------------
// fused pack: blocks [0,2048) = input fp32->bf16; [2048,2816) = weight
// transpose (H,E,D) fp32 -> (H,D,E) bf16.
// ---------------------------------------------------------------------------
__global__ __launch_bounds__(256) void pack_kernel(
    const float* __restrict__ in, unsigned short* __restrict__ o16,
    const float* __restrict__ qw, const float* __restrict__ kw, const float* __restrict__ vw,
    unsigned short* __restrict__ qwt, unsigned short* __restrict__ kwt,
    unsigned short* __restrict__ vwt)
{
  __shared__ float s[64][65];
  const int tid = threadIdx.x;
  if (blockIdx.x < 2048) {                       // input pack
    const size_t i = ((size_t)blockIdx.x * 256 + tid) * 8;
    float4 f0 = *(const float4*)(in + i);
    float4 f1 = *(const float4*)(in + i + 4);
    unsigned u[4] = { pk2bf(f0.x, f0.y), pk2bf(f0.z, f0.w),
                      pk2bf(f1.x, f1.y), pk2bf(f1.z, f1.w) };
    *(bf16x8*)(o16 + i) = *(const bf16x8*)u;
    return;
  }
  const int i = blockIdx.x - 2048;
  const int e0 = (i & 15) * 64, h = (i >> 4) & 15, z = i >> 8;
  const float* w = (z == 0) ? qw : (z == 1) ? kw : vw;
  unsigned short* o = (z == 0) ? qwt : (z == 1) ? kwt : vwt;
  {
    const int r = tid >> 2;
    #pragma unroll
    for (int p = 0; p < 4; ++p) {
      const int c = (tid & 3) * 4 + p * 16;
      float4 f = *(const float4*)(w + ((size_t)(h * E_ + e0 + r)) * D_ + c);
      s[r][c] = f.x; s[r][c+1] = f.y; s[r][c+2] = f.z; s[r][c+3] = f.w;
    }
  }
  __syncthreads();
  {
    const int d = tid >> 2, ec = (tid & 3) * 16;
    unsigned short tmp[16];
    #pragma unroll
    for (int j = 0; j < 16; ++j) tmp[j] = f2bf(s[ec + j][d]);
    unsigned short* dst = o + ((size_t)(h * D_ + d)) * E_ + e0 + ec;
    *(bf16x8*)(dst)     = *(const bf16x8*)&tmp[0];
    *(bf16x8*)(dst + 8) = *(const bf16x8*)&tmp[8];
  }
}

// ---------------------------------------------------------------------------
// QKV projection. Flat grid 512 with XCD-affine head mapping: dispatch
// round-robins linear id across the 8 XCDs, so h = 2*(lin&7)+((lin>>3)&1)
// pins heads {2x,2x+1} to XCD x -> per-XCD weight working set 768 KB
// (L2-resident; was 6 MB thrashing to L3 with grid (16,16,2) where
// XCD = t0%8 saw all 16 heads). Body identical to round-1 (best anchor):
// wave retile, 22 LDS frag reads/wave/iter, BK=64, dbuf dma8 staging.
// ---------------------------------------------------------------------------
__global__ __launch_bounds__(256) void proj_kernel(
    const unsigned short* __restrict__ in16,
    const unsigned short* __restrict__ qwt, const unsigned short* __restrict__ kwt,
    const unsigned short* __restrict__ vwt,
    const float* __restrict__ qb, const float* __restrict__ kb, const float* __restrict__ vb,
    unsigned short* __restrict__ qo, unsigned short* __restrict__ ko,
    unsigned short* __restrict__ vt)
{
  __shared__ __align__(16) unsigned short in_s[2][128 * 64];   // 32 KB
  __shared__ __align__(16) unsigned short w_s[2][3 * 64 * 64]; // 48 KB (flat rows: x*64+d)
  const int tid = threadIdx.x;
  const int lane = tid & 63, wv = tid >> 6;
  const int l15 = lane & 15, quad = lane >> 4;
  // XCD-affine remap (bijective over 512): heads {2x,2x+1} -> XCD x
  const int lin = blockIdx.x;
  const int h = ((lin & 7) << 1) | ((lin >> 3) & 1);
  const int rem = lin >> 4;                      // 0..31
  const int t0 = (rem & 15) * 128, b = rem >> 4;
  const int bh = b * H_ + h;
  const unsigned short* wts[3] = { qwt, kwt, vwt };

  f32x4 acc[3][8];
  #pragma unroll
  for (int x = 0; x < 3; ++x)
    #pragma unroll
    for (int tb = 0; tb < 8; ++tb) acc[x][tb] = (f32x4){0.f, 0.f, 0.f, 0.f};

#define PROJ_STAGE(e0_, bi_)                                                      \
  {                                                                               \
    const unsigned short* gin = in16 + ((size_t)(b * T_ + t0)) * E_ + (e0_);      \
    _Pragma("unroll")                                                             \
    for (int p = 0; p < 4; ++p) {                                                 \
      const int br = wv * 32 + p * 8;                                             \
      dma8(gin + (size_t)br * E_, E_, &in_s[bi_][br * 64], lane);                 \
    }                                                                             \
    _Pragma("unroll")                                                             \
    for (int j = 0; j < 6; ++j) {                                                 \
      const int idx = wv * 6 + j;                                                 \
      const int x = idx >> 3, br = (idx & 7) * 8;                                 \
      dma8(wts[x] + ((size_t)(h * D_ + br)) * E_ + (e0_), E_,                     \
           &w_s[bi_][x * 4096 + br * 64], lane);                                  \
    }                                                                             \
  }

  PROJ_STAGE(0, 0);
  __syncthreads();
  for (int e = 0; e < 16; ++e) {
    const int bi = e & 1;
    if (e < 15) PROJ_STAGE((e + 1) * 64, bi ^ 1);
    const unsigned short* is = in_s[bi];
    const unsigned short* ws = w_s[bi];
    #pragma unroll
    for (int kk = 0; kk < 2; ++kk) {
      const int g0 = kk * 4 + quad;
      bf16x8 bfr[3];
      #pragma unroll
      for (int x = 0; x < 3; ++x)
        bfr[x] = frag(ws, x * 64 + wv * 16 + l15, g0);
      bf16x8 afr[8];
      #pragma unroll
      for (int tb = 0; tb < 8; ++tb)
        afr[tb] = frag(is, tb * 16 + l15, g0);
      #pragma unroll
      for (int tb = 0; tb < 8; ++tb) {
        // q,k: A=w (m=d), B=in (n=t) -> C col=t; v: A=in (m=t), B=w -> C col=d
        acc[0][tb] = __builtin_amdgcn_mfma_f32_16x16x32_bf16(bfr[0], afr[tb], acc[0][tb], 0, 0, 0);
        acc[1][tb] = __builtin_amdgcn_mfma_f32_16x16x32_bf16(bfr[1], afr[tb], acc[1][tb], 0, 0, 0);
        acc[2][tb] = __builtin_amdgcn_mfma_f32_16x16x32_bf16(afr[tb], bfr[2], acc[2][tb], 0, 0, 0);
      }
    }
    __syncthreads();
  }
#undef PROJ_STAGE

  const size_t obase = (size_t)bh * T_;
  // q (scaled) and k: lane t = tb*16+l15, 4 consecutive d -> ushort4 stores
  #pragma unroll
  for (int x = 0; x < 2; ++x) {
    const float scl = (x == 0) ? QSCALE : 1.0f;
    const float* bias = (x == 0) ? qb : kb;
    unsigned short* outp = (x == 0) ? qo : ko;
    float bias4[4];
    *(float4*)bias4 = *(const float4*)&bias[h * D_ + wv * 16 + quad * 4];
    #pragma unroll
    for (int tb = 0; tb < 8; ++tb) {
      const int t = t0 + tb * 16 + l15;
      unsigned short pk[4];
      #pragma unroll
      for (int r = 0; r < 4; ++r) pk[r] = f2bf((acc[x][tb][r] + bias4[r]) * scl);
      *(ushort4*)(outp + (obase + t) * D_ + wv * 16 + quad * 4) = *(const ushort4*)pk;
    }
  }
  // v: transposed [d][t] — lane d = wv*16+l15, 4 consecutive t -> ushort4
  {
    const int d = wv * 16 + l15;
    const float bvv = vb[h * D_ + d];
    #pragma unroll
    for (int tb = 0; tb < 8; ++tb) {
      const int t = t0 + tb * 16 + quad * 4;
      unsigned short pk[4];
      #pragma unroll
      for (int r = 0; r < 4; ++r) pk[r] = f2bf(acc[2][tb][r] + bvv);
      *(ushort4*)(vt + ((size_t)(bh * D_ + d)) * T_ + t) = *(const ushort4*)pk;
    }
  }
}

// ---------------------------------------------------------------------------
// Column softmax: lg[s] = -log2( sum_t exp2(S'[t,s]) ). grid (H, B, NT) =
// 1024 blocks; sa=0 (heaviest) first. K B-frags reg-resident.
// BARRIER-FREE main loop [round-7 form, best total 169.1 us]: wave wv stages
// and reads ONLY rows [wv*16, wv*16+16) -> zero cross-wave LDS sharing.
// Tri-buffered q_s[3], per-wave pipeline paced by own counted vmcnt(2).
// ---------------------------------------------------------------------------
__global__ __launch_bounds__(256) void stats_kernel(
    const unsigned short* __restrict__ q, const unsigned short* __restrict__ k,
    float* __restrict__ lg)
{
  __shared__ __align__(16) unsigned short q_s[3][64 * 64];   // 24 KB tri-buffer
  __shared__ float red[4][64];
  const int tid = threadIdx.x;
  const int lane = tid & 63, wv = tid >> 6;
  const int l15 = lane & 15, quad = lane >> 4;
  const int h = blockIdx.x, b = blockIdx.y, sa = blockIdx.z;
  const int bh = b * H_ + h;
  const int s0 = sa * 64;
  const unsigned short* qbase = q + (size_t)bh * T_ * 64;

  bf16x8 kf[4][2];                               // reg-resident K B-frags (one-time)
  #pragma unroll
  for (int nb = 0; nb < 4; ++nb)
    #pragma unroll
    for (int kk = 0; kk < 2; ++kk)
      kf[nb][kk] = *(const bf16x8*)(k + ((size_t)(bh * T_ + s0 + nb * 16 + l15)) * 64
                                      + kk * 32 + quad * 8);

#define ST_STAGE(tt_, slot_)                                                 \
  { _Pragma("unroll")                                                        \
    for (int pp = 0; pp < 2; ++pp) {                                         \
      const int br = wv * 16 + pp * 8;                                       \
      dma8(qbase + (size_t)((tt_) * 64 + br) * 64, 64, &q_s[slot_][br * 64], lane); \
    } }

  ST_STAGE(sa, 0);
  if (sa + 1 < NT_) ST_STAGE(sa + 1, 1);

  float lsum[4] = {0.f, 0.f, 0.f, 0.f};

  for (int tt = sa; tt < NT_; ++tt) {
    const int i = tt - sa;
    // own stage(tt) retired; stage(tt+1) (2 ops) may stay in flight
    if (tt + 1 < NT_) asm volatile("s_waitcnt vmcnt(2)" ::: "memory");
    else              asm volatile("s_waitcnt vmcnt(0)" ::: "memory");
    __builtin_amdgcn_sched_barrier(0);           // don't hoist reads above the wait

    const unsigned short* qs = q_s[i % 3];
    bf16x8 a0 = frag(qs, wv * 16 + l15, quad);
    bf16x8 a1 = frag(qs, wv * 16 + l15, 4 + quad);
    if (tt + 2 < NT_) ST_STAGE(tt + 2, (i + 2) % 3);

    f32x4 sacc[4];
    #pragma unroll
    for (int nb = 0; nb < 4; ++nb) sacc[nb] = (f32x4){0.f, 0.f, 0.f, 0.f};
    #pragma unroll
    for (int nb = 0; nb < 4; ++nb) {
      sacc[nb] = __builtin_amdgcn_mfma_f32_16x16x32_bf16(a0, kf[nb][0], sacc[nb], 0, 0, 0);
      sacc[nb] = __builtin_amdgcn_mfma_f32_16x16x32_bf16(a1, kf[nb][1], sacc[nb], 0, 0, 0);
    }
    if (tt == sa) {                              // diagonal tile: causal mask
      const int tbase = tt * 64 + wv * 16 + quad * 4;
      #pragma unroll
      for (int nb = 0; nb < 4; ++nb) {
        const int s = s0 + nb * 16 + l15;
        #pragma unroll
        for (int r = 0; r < 4; ++r)
          lsum[nb] += (tbase + r >= s) ? EXP2(sacc[nb][r]) : 0.f;
      }
    } else {
      #pragma unroll
      for (int nb = 0; nb < 4; ++nb)
        #pragma unroll
        for (int r = 0; r < 4; ++r) lsum[nb] += EXP2(sacc[nb][r]);
    }
  }
#undef ST_STAGE
  #pragma unroll
  for (int nb = 0; nb < 4; ++nb) {
    lsum[nb] += __shfl_xor(lsum[nb], 16);
    lsum[nb] += __shfl_xor(lsum[nb], 32);
  }
  if (lane < 16) {
    #pragma unroll
    for (int nb = 0; nb < 4; ++nb) red[wv][nb * 16 + lane] = lsum[nb];
  }
  __syncthreads();                               // only cross-wave sync point
  if (tid < 64) {
    const float L = red[0][tid] + red[1][tid] + red[2][tid] + red[3][tid];
    lg[(size_t)bh * T_ + s0 + tid] = -__log2f(L);
  }
}

// ---------------------------------------------------------------------------
// Output. grid (H, B, NT) = 1024 blocks, jt = 31-z heavy-first. K/Vt/lg
// DOUBLE-BUFFERED dma8 (42.7 KB LDS -> 3 blocks/CU). Quadrant ownership:
// wave (th,sh) owns 32t x 32s. U wave-private. Diagonal (th=0,sh=1) skipped.
// End: O partials reduced through retired k_s. [round-1 form]
// ---------------------------------------------------------------------------
__global__ __launch_bounds__(256) void out_kernel(
    const unsigned short* __restrict__ q, const unsigned short* __restrict__ k,
    const unsigned short* __restrict__ vt, const float* __restrict__ lg,
    float* __restrict__ out)
{
  __shared__ __align__(16) unsigned short k_s[2][64 * 64];    // 16 KB (reused as O-scratch)
  __shared__ __align__(16) unsigned short vt_s[2][64 * 64];   // 16 KB
  __shared__ __align__(16) unsigned short u_s[4][32][40];     // 10 KB wave-private U quadrants
  __shared__ float lg_sh[2][64];
  const int tid = threadIdx.x;
  const int lane = tid & 63, wv = tid >> 6;
  const int l15 = lane & 15, quad = lane >> 4;
  const int th = wv >> 1, sh = wv & 1;           // wave's t-half / s-half
  const int h = blockIdx.x, b = blockIdx.y, jt = 31 - blockIdx.z;
  const int bh = b * H_ + h;
  const int t0 = jt * 64;
  const unsigned short* kbase = k + (size_t)bh * T_ * 64;
  const unsigned short* vbase = vt + (size_t)bh * D_ * T_;
  const float* lgbase = lg + (size_t)bh * T_;

  // one-time Q B-frags: this wave's 32 t-cols (2 n-tiles x 2 k-steps)
  bf16x8 qf[2][2];
  #pragma unroll
  for (int nt = 0; nt < 2; ++nt) {
    const unsigned short* qrow = q + (size_t)(bh * T_ + t0 + th * 32 + nt * 16 + l15) * 64;
    qf[nt][0] = *(const bf16x8*)(qrow + quad * 8);
    qf[nt][1] = *(const bf16x8*)(qrow + 32 + quad * 8);
  }

  // stage unit 0 into slot 0
  #pragma unroll
  for (int pp = 0; pp < 2; ++pp) {
    const int br = wv * 16 + pp * 8;
    dma8(kbase + (size_t)br * 64, 64, &k_s[0][br * 64], lane);
    dma8(vbase + (size_t)br * T_, T_, &vt_s[0][br * 64], lane);
  }
  if (tid < 64) lg_sh[0][tid] = lgbase[tid];
  __syncthreads();

  f32x4 oacc[4][2];                              // [d-tile][t-tile of own half]
  #pragma unroll
  for (int mb = 0; mb < 4; ++mb)
    #pragma unroll
    for (int nt = 0; nt < 2; ++nt) oacc[mb][nt] = (f32x4){0.f, 0.f, 0.f, 0.f};

  for (int st = 0; st <= jt; ++st) {
    const int bi = st & 1;
    if (st < jt) {                               // prefetch next unit
      const int s1 = (st + 1) * 64;
      #pragma unroll
      for (int pp = 0; pp < 2; ++pp) {
        const int br = wv * 16 + pp * 8;
        dma8(kbase + (size_t)(s1 + br) * 64, 64, &k_s[bi ^ 1][br * 64], lane);
        dma8(vbase + (size_t)br * T_ + s1, T_, &vt_s[bi ^ 1][br * 64], lane);
      }
      if (tid < 64) lg_sh[bi ^ 1][tid] = lgbase[s1 + tid];
    }
    const unsigned short* ks = k_s[bi];
    const unsigned short* vs = vt_s[bi];
    const float* lgb = lg_sh[bi];

    const bool dead = (st == jt) && (th == 0) && (sh == 1);  // fully-masked quadrant
    if (!dead) {
      // S^T quadrant: A = K rows (own s-half), B = Q (reg); C init = lg[s]
      f32x4 sacc[2][2];
      #pragma unroll
      for (int mb = 0; mb < 2; ++mb) {
        float lg4[4];
        *(float4*)lg4 = *(const float4*)&lgb[sh * 32 + mb * 16 + quad * 4];
        #pragma unroll
        for (int nt = 0; nt < 2; ++nt)
          sacc[mb][nt] = (f32x4){lg4[0], lg4[1], lg4[2], lg4[3]};
      }
      #pragma unroll
      for (int mb = 0; mb < 2; ++mb) {
        bf16x8 ka0 = frag(ks, sh * 32 + mb * 16 + l15, quad);
        bf16x8 ka1 = frag(ks, sh * 32 + mb * 16 + l15, 4 + quad);
        #pragma unroll
        for (int nt = 0; nt < 2; ++nt) {
          sacc[mb][nt] = __builtin_amdgcn_mfma_f32_16x16x32_bf16(ka0, qf[nt][0], sacc[mb][nt], 0, 0, 0);
          sacc[mb][nt] = __builtin_amdgcn_mfma_f32_16x16x32_bf16(ka1, qf[nt][1], sacc[mb][nt], 0, 0, 0);
        }
      }
      // U = exp2(S' + lg[s]); diagonal quadrants (th==sh) masked elementwise
      const bool diagmask = (st == jt) && (th == sh);
      #pragma unroll
      for (int mb = 0; mb < 2; ++mb)
        #pragma unroll
        for (int nt = 0; nt < 2; ++nt) {
          float uu[4] = { EXP2(sacc[mb][nt][0]), EXP2(sacc[mb][nt][1]),
                          EXP2(sacc[mb][nt][2]), EXP2(sacc[mb][nt][3]) };
          if (diagmask) {
            const int tl = nt * 16 + l15, sl = mb * 16 + quad * 4;
            #pragma unroll
            for (int r = 0; r < 4; ++r) if (tl < sl + r) uu[r] = 0.f;
          }
          *(uint2*)(&u_s[wv][nt * 16 + l15][mb * 16 + quad * 4]) =
              make_uint2(pk2bf(uu[0], uu[1]), pk2bf(uu[2], uu[3]));
        }
      // O^T partial += Vt[:, own s-half] . U^T — same-wave LDS dep, K-dim=32
      #pragma unroll
      for (int nt = 0; nt < 2; ++nt) {
        bf16x8 ua = *(const bf16x8*)(&u_s[wv][nt * 16 + l15][quad * 8]);
        #pragma unroll
        for (int mb = 0; mb < 4; ++mb)
          oacc[mb][nt] = __builtin_amdgcn_mfma_f32_16x16x32_bf16(
              frag(vs, mb * 16 + l15, sh * 4 + quad), ua, oacc[mb][nt], 0, 0, 0);
      }
    }
    __syncthreads();   // waves done with slot bi; prefetch into bi^1 drained
  }

  // cross-wave reduce over s-halves: sh=1 writes partials to retired k_s (fp32)
  float* scr = (float*)k_s;                      // 16 KB = 2 th x 8 acc x 64 lanes x 16B
  if (sh == 1) {
    #pragma unroll
    for (int mb = 0; mb < 4; ++mb)
      #pragma unroll
      for (int nt = 0; nt < 2; ++nt) {
        float o4[4] = { oacc[mb][nt][0], oacc[mb][nt][1], oacc[mb][nt][2], oacc[mb][nt][3] };
        *(float4*)&scr[((th * 8 + mb * 2 + nt) * 64 + lane) * 4] = *(const float4*)o4;
      }
  }
  __syncthreads();
  if (sh == 0) {
    #pragma unroll
    for (int nt = 0; nt < 2; ++nt) {
      float* orow = out + ((size_t)(b * T_ + t0 + th * 32 + nt * 16 + l15)) * (H_ * D_) + h * D_;
      #pragma unroll
      for (int mb = 0; mb < 4; ++mb) {
        float4 p = *(const float4*)&scr[((th * 8 + mb * 2 + nt) * 64 + lane) * 4];
        float o4[4] = { oacc[mb][nt][0] + p.x, oacc[mb][nt][1] + p.y,
                        oacc[mb][nt][2] + p.z, oacc[mb][nt][3] + p.w };
        *(float4*)(orow + mb * 16 + quad * 4) = *(const float4*)o4;
      }
    }
  }
}

extern "C" void kernel_launch(void* const* d_in, const int* in_sizes, int n_in,
                              void* d_out, int out_size, void* d_ws, size_t ws_size,
                              hipStream_t stream) {
  const float* in = (const float*)d_in[0];
  const float* kw = (const float*)d_in[1];
  const float* kb = (const float*)d_in[2];
  const float* qw = (const float*)d_in[3];
  const float* qb = (const float*)d_in[4];
  const float* vw = (const float*)d_in[5];
  const float* vb = (const float*)d_in[6];
  float* out = (float*)d_out;

  // ws (bf16): in16 | qwt|kwt|vwt (H,D,E) | q16|k16 (B,H,T,D) | vt (B,H,D,T) | lg fp32
  unsigned short* p = (unsigned short*)d_ws;
  const size_t inz = (size_t)B_ * T_ * E_;
  const size_t wz  = (size_t)H_ * D_ * E_;
  const size_t qz  = (size_t)B_ * H_ * T_ * D_;
  unsigned short* in16 = p;            p += inz;
  unsigned short* qwt  = p;            p += wz;
  unsigned short* kwt  = p;            p += wz;
  unsigned short* vwt  = p;            p += wz;
  unsigned short* q16  = p;            p += qz;
  unsigned short* k16  = p;            p += qz;
  unsigned short* vtb  = p;            p += qz;
  float* lgbuf = (float*)p;

  dim3 blk(256);
  pack_kernel <<<dim3(2048 + 768), blk, 0, stream>>>(in, in16, qw, kw, vw, qwt, kwt, vwt);
  proj_kernel <<<dim3(512), blk, 0, stream>>>(in16, qwt, kwt, vwt,
                                              qb, kb, vb, q16, k16, vtb);
  stats_kernel<<<dim3(H_, B_, NT_), blk, 0, stream>>>(q16, k16, lgbuf);
  out_kernel  <<<dim3(H_, B_, NT_), blk, 0, stream>>>(q16, k16, vtb, lgbuf, out);
}